// Round 3
// baseline (385.038 us; speedup 1.0000x reference)
//
#include <hip/hip_runtime.h>

#define NH   12
#define SEQ  1024
#define NB   8
#define DCAT 96
#define DV   80

typedef __attribute__((ext_vector_type(8))) short  bf16x8;
typedef __attribute__((ext_vector_type(4))) float  f32x4;
typedef __attribute__((ext_vector_type(4))) unsigned short u16x4;

static __device__ __forceinline__ unsigned short f2bf(float x) {
    unsigned int u = __float_as_uint(x);
    u += 0x7fffu + ((u >> 16) & 1u);   // RNE
    return (unsigned short)(u >> 16);
}
static __device__ __forceinline__ f32x4 fzero() {
    f32x4 z; z[0]=0.f; z[1]=0.f; z[2]=0.f; z[3]=0.f; return z;
}

#define GLDS16(gp, lp) __builtin_amdgcn_global_load_lds(                      \
    (const __attribute__((address_space(1))) void*)(gp),                      \
    (__attribute__((address_space(3))) void*)(lp), 16, 0, 0)

// ---------------- f32 -> bf16 convert ----------------
__global__ __launch_bounds__(256) void cvt_kernel(
    const float* __restrict__ in, unsigned short* __restrict__ out, int n4)
{
    int i = blockIdx.x * 256 + threadIdx.x;
    if (i >= n4) return;
    f32x4 v = ((const f32x4*)in)[i];
    u16x4 o;
    o[0] = f2bf(v[0]); o[1] = f2bf(v[1]); o[2] = f2bf(v[2]); o[3] = f2bf(v[3]);
    ((u16x4*)out)[i] = o;
}

// ---------------- fused projection GEMM ----------------
// C[8192, Ntot] = A[8192,K] @ Bw[Ntot,K]^T, epilogue scatters into Qc/Kc/VT.
// variant 0: Ntot=2304 (Q|K|V, seg 768), variant 1: Ntot=576 (LQ|LK|LV, seg 192)
// variant 1 also writes the d=80..95 zero pad of Qc/Kc (replaces memset).
__global__ __launch_bounds__(256) void proj_gemm(
    const unsigned short* __restrict__ A,
    const unsigned short* __restrict__ Bw,
    const float* __restrict__ b0, const float* __restrict__ b1, const float* __restrict__ b2,
    unsigned short* __restrict__ Qc, unsigned short* __restrict__ Kc, unsigned short* __restrict__ VT,
    int K, int Ntot, int variant)
{
    __shared__ __align__(16) unsigned short As[4096];   // [128][32]
    __shared__ __align__(16) unsigned short Bs[4096];   // [128][32]
    const int tid = threadIdx.x, w = tid >> 6, lane = tid & 63;
    const int g = lane >> 4, c = lane & 15;
    const int m0 = blockIdx.x * 128, n0 = blockIdx.y * 128;
    const int wr = w >> 1, wc = w & 1;
    const int srow = lane >> 2, scol = (lane & 3) * 8;

    f32x4 acc[4][4];
    #pragma unroll
    for (int m = 0; m < 4; m++)
        #pragma unroll
        for (int n = 0; n < 4; n++) acc[m][n] = fzero();

    const int ch0 = w * 2, ch1 = w * 2 + 1;
    const size_t arow0 = (size_t)(m0 + ch0 * 16 + srow) * K + scol;
    const size_t arow1 = (size_t)(m0 + ch1 * 16 + srow) * K + scol;
    int bn0 = n0 + ch0 * 16 + srow; if (bn0 >= Ntot) bn0 = Ntot - 1;
    int bn1 = n0 + ch1 * 16 + srow; if (bn1 >= Ntot) bn1 = Ntot - 1;
    const size_t brow0 = (size_t)bn0 * K + scol;
    const size_t brow1 = (size_t)bn1 * K + scol;

    for (int k0 = 0; k0 < K; k0 += 32) {
        __syncthreads();
        GLDS16(A  + arow0 + k0, As + ch0 * 512);
        GLDS16(A  + arow1 + k0, As + ch1 * 512);
        GLDS16(Bw + brow0 + k0, Bs + ch0 * 512);
        GLDS16(Bw + brow1 + k0, Bs + ch1 * 512);
        __syncthreads();
        bf16x8 af[4], bfr[4];
        #pragma unroll
        for (int m = 0; m < 4; m++) af[m]  = *(const bf16x8*)&As[(wr*64 + m*16 + c)*32 + g*8];
        #pragma unroll
        for (int n = 0; n < 4; n++) bfr[n] = *(const bf16x8*)&Bs[(wc*64 + n*16 + c)*32 + g*8];
        #pragma unroll
        for (int m = 0; m < 4; m++)
            #pragma unroll
            for (int n = 0; n < 4; n++)
                acc[m][n] = __builtin_amdgcn_mfma_f32_16x16x32_bf16(af[m], bfr[n], acc[m][n], 0, 0, 0);
    }

    // epilogue: scatter with bias + scale into head layouts
    const int b_ = m0 >> 10;
    #pragma unroll
    for (int nf = 0; nf < 4; nf++) {
        int n = n0 + wc * 64 + nf * 16 + c;
        if (n >= Ntot) continue;
        int seg, nn;
        if (variant == 0) { seg = (n >= 1536) ? 2 : ((n >= 768) ? 1 : 0); nn = n - seg * 768; }
        else              { seg = (n >= 384)  ? 2 : ((n >= 192) ? 1 : 0); nn = n - seg * 192; }
        const float* bp = (seg == 0) ? b0 : ((seg == 1) ? b1 : b2);
        float bv = bp[nn];
        float scale = (seg == 0) ? (variant ? 0.25f : 0.125f) : 1.0f;
        int h, d;
        if (variant == 0) { h = nn >> 6; d = nn & 63; }
        else              { h = nn >> 4; d = 64 + (nn & 15); }
        #pragma unroll
        for (int m = 0; m < 4; m++) {
            int row = m0 + wr * 64 + m * 16 + 4 * g;
            int s = row & 1023;
            if (seg < 2) {
                unsigned short* dst = (seg == 0) ? Qc : Kc;
                size_t base = (size_t)(b_ * NH + h) * SEQ;
                #pragma unroll
                for (int r = 0; r < 4; r++) {
                    dst[(base + s + r) * DCAT + d] = f2bf((acc[m][nf][r] + bv) * scale);
                    if (variant == 1)
                        dst[(base + s + r) * DCAT + d + 16] = 0;   // zero pad d=80..95
                }
            } else {
                u16x4 pk;
                #pragma unroll
                for (int r = 0; r < 4; r++) pk[r] = f2bf(acc[m][nf][r] + bv);
                *(u16x4*)&VT[((size_t)(b_ * NH + h) * DV + d) * SEQ + s] = pk;
            }
        }
    }
}

// ---------------- fused attention: 2-pass max-free softmax ----------------
// grid: 1536 blocks (XCD-swizzled). 4 waves, each owns 16 q rows.
// K tiles (64 k-rows) staged in LDS, shared by all 4 waves, bank-balanced
// 3-plane layout Ks[plane][row][32shorts].
__global__ __launch_bounds__(256) void attn_kernel(
    const unsigned short* __restrict__ Qc,   // [BH, SEQ, 96] bf16: q/8 | lq/4 | 0
    const unsigned short* __restrict__ Kc,   // [BH, SEQ, 96] bf16: k | lk | 0
    const unsigned short* __restrict__ VT,   // [BH, 80, SEQ] bf16 (d-major)
    const float* __restrict__ mask,          // [NB, SEQ]
    float* __restrict__ ctx,                 // [NB, SEQ, 768]
    float* __restrict__ lctx,                // [NB, SEQ, 192]
    float* __restrict__ probs)               // [BH, SEQ, SEQ]
{
    __shared__ __align__(16) unsigned short Ks[3 * 64 * 32];   // 12 KiB
    __shared__ __align__(16) float sbuf[4][16][36];            // 9216 B

    const int tid = threadIdx.x, w = tid >> 6, lane = tid & 63;
    const int g = lane >> 4, c = lane & 15;

    // XCD-bijective swizzle: all 16 q-tiles of one bh land consecutively on one XCD
    const int bid = blockIdx.x;
    const int xc = bid & 7, j = bid >> 3;     // j in 0..191
    const int bh = xc + 8 * (j >> 4);         // 0..95
    const int qt = j & 15;
    const int b = bh / NH, h = bh % NH;
    const int qrb = qt * 64 + w * 16;
    const float NEGF = -3.4028234663852886e38f;

    // Q fragments (persist whole kernel)
    bf16x8 qf0, qf1, qf2;
    {
        const unsigned short* qrow = &Qc[((size_t)bh * SEQ + qrb + c) * DCAT + g * 8];
        qf0 = *(const bf16x8*)(qrow);
        qf1 = *(const bf16x8*)(qrow + 32);
        qf2 = *(const bf16x8*)(qrow + 64);
    }
    const unsigned short* Kb = Kc + (size_t)bh * SEQ * DCAT;
    const unsigned short* Vb = VT + (size_t)bh * DV * SEQ;
    const float* mk = mask + b * SEQ;

    // staging geometry: tile = 64 k-rows x 96 = 12288 B = 768 x 16B chunks,
    // thread handles chunks m = r*256+tid (r=0..2)
    int src_s[3], dst_s[3];
    #pragma unroll
    for (int r = 0; r < 3; r++) {
        int m = r * 256 + tid;
        int row = m / 12, c16 = m % 12;
        src_s[r] = m * 8;                                          // shorts
        dst_s[r] = (c16 >> 2) * 2048 + row * 32 + (c16 & 3) * 8;   // shorts
    }

    // ---- pass A: per-lane partial sum of exp(s) ----
    float sm[4] = {0.f, 0.f, 0.f, 0.f};
    for (int tile = 0; tile < 16; tile++) {
        __syncthreads();
        bf16x8 t0 = *(const bf16x8*)(Kb + tile * 6144 + src_s[0]);
        bf16x8 t1 = *(const bf16x8*)(Kb + tile * 6144 + src_s[1]);
        bf16x8 t2 = *(const bf16x8*)(Kb + tile * 6144 + src_s[2]);
        *(bf16x8*)&Ks[dst_s[0]] = t0;
        *(bf16x8*)&Ks[dst_s[1]] = t1;
        *(bf16x8*)&Ks[dst_s[2]] = t2;
        __syncthreads();
        #pragma unroll
        for (int kt = 0; kt < 4; kt++) {
            int lr = kt * 16 + c;
            f32x4 a = fzero();
            a = __builtin_amdgcn_mfma_f32_16x16x32_bf16(qf0, *(const bf16x8*)&Ks[         lr * 32 + g * 8], a, 0,0,0);
            a = __builtin_amdgcn_mfma_f32_16x16x32_bf16(qf1, *(const bf16x8*)&Ks[2048 +   lr * 32 + g * 8], a, 0,0,0);
            a = __builtin_amdgcn_mfma_f32_16x16x32_bf16(qf2, *(const bf16x8*)&Ks[4096 +   lr * 32 + g * 8], a, 0,0,0);
            float bias = (1.0f - mk[tile * 64 + lr]) * NEGF;
            #pragma unroll
            for (int r = 0; r < 4; r++) sm[r] += __expf(a[r] + bias);
        }
    }
    #pragma unroll
    for (int off = 8; off >= 1; off >>= 1)
        #pragma unroll
        for (int r = 0; r < 4; r++) sm[r] += __shfl_xor(sm[r], off);
    float rinv[4];
    #pragma unroll
    for (int r = 0; r < 4; r++) rinv[r] = 1.0f / fmaxf(sm[r], 1e-38f);

    // ---- pass B: recompute scores, write probs (coalesced), PV accumulate ----
    f32x4 cacc[5];
    #pragma unroll
    for (int nf = 0; nf < 5; nf++) cacc[nf] = fzero();

    const int prow = lane >> 3, pcb = lane & 7;
    const size_t pbase = ((size_t)bh * SEQ + qrb) * SEQ;

    for (int tile = 0; tile < 16; tile++) {
        __syncthreads();
        bf16x8 t0 = *(const bf16x8*)(Kb + tile * 6144 + src_s[0]);
        bf16x8 t1 = *(const bf16x8*)(Kb + tile * 6144 + src_s[1]);
        bf16x8 t2 = *(const bf16x8*)(Kb + tile * 6144 + src_s[2]);
        *(bf16x8*)&Ks[dst_s[0]] = t0;
        *(bf16x8*)&Ks[dst_s[1]] = t1;
        *(bf16x8*)&Ks[dst_s[2]] = t2;
        __syncthreads();
        #pragma unroll
        for (int kp2 = 0; kp2 < 2; kp2++) {
            int kp = tile * 2 + kp2;
            #pragma unroll
            for (int ph = 0; ph < 2; ph++) {
                int lr = kp2 * 32 + ph * 16 + c;
                f32x4 a = fzero();
                a = __builtin_amdgcn_mfma_f32_16x16x32_bf16(qf0, *(const bf16x8*)&Ks[       lr * 32 + g * 8], a, 0,0,0);
                a = __builtin_amdgcn_mfma_f32_16x16x32_bf16(qf1, *(const bf16x8*)&Ks[2048 + lr * 32 + g * 8], a, 0,0,0);
                a = __builtin_amdgcn_mfma_f32_16x16x32_bf16(qf2, *(const bf16x8*)&Ks[4096 + lr * 32 + g * 8], a, 0,0,0);
                float bias = (1.0f - mk[tile * 64 + lr]) * NEGF;
                #pragma unroll
                for (int r = 0; r < 4; r++)
                    sbuf[w][4 * g + r][ph * 16 + c] = __expf(a[r] + bias) * rinv[r];
            }
            // coalesced probs store: lanes 0..7 cover one full 128B row segment
            f32x4 pv0 = *(const f32x4*)&sbuf[w][prow][pcb * 4];
            f32x4 pv1 = *(const f32x4*)&sbuf[w][8 + prow][pcb * 4];
            *(f32x4*)&probs[pbase + (size_t)prow * SEQ + kp * 32 + pcb * 4] = pv0;
            *(f32x4*)&probs[pbase + (size_t)(8 + prow) * SEQ + kp * 32 + pcb * 4] = pv1;

            // PV A-fragment from sbuf (row = q, cols = k-chunk)
            f32x4 pa0 = *(const f32x4*)&sbuf[w][c][g * 8];
            f32x4 pa1 = *(const f32x4*)&sbuf[w][c][g * 8 + 4];
            bf16x8 pa;
            #pragma unroll
            for (int jj = 0; jj < 4; jj++) { pa[jj] = (short)f2bf(pa0[jj]); pa[4 + jj] = (short)f2bf(pa1[jj]); }
            #pragma unroll
            for (int nf = 0; nf < 5; nf++) {
                bf16x8 vf = *(const bf16x8*)&Vb[(size_t)(nf * 16 + c) * SEQ + kp * 32 + g * 8];
                cacc[nf] = __builtin_amdgcn_mfma_f32_16x16x32_bf16(pa, vf, cacc[nf], 0, 0, 0);
            }
        }
    }

    // ---- epilogue ----
    #pragma unroll
    for (int nf = 0; nf < 4; nf++)
        #pragma unroll
        for (int r = 0; r < 4; r++) {
            int q = qrb + 4 * g + r;
            ctx[((size_t)(b * SEQ + q)) * 768 + h * 64 + nf * 16 + c] = cacc[nf][r];
        }
    #pragma unroll
    for (int r = 0; r < 4; r++) {
        int q = qrb + 4 * g + r;
        lctx[((size_t)(b * SEQ + q)) * 192 + h * 16 + c] = cacc[4][r];
    }
}

// ---------------- host launch ----------------
extern "C" void kernel_launch(void* const* d_in, const int* in_sizes, int n_in,
                              void* d_out, int out_size, void* d_ws, size_t ws_size,
                              hipStream_t stream)
{
    const float* hs   = (const float*)d_in[0];
    const float* lhs  = (const float*)d_in[1];
    const float* mask = (const float*)d_in[2];
    const float* Wq   = (const float*)d_in[3];
    const float* bq   = (const float*)d_in[4];
    const float* Wk   = (const float*)d_in[5];
    const float* bk   = (const float*)d_in[6];
    const float* Wv   = (const float*)d_in[7];
    const float* bv   = (const float*)d_in[8];
    const float* Wlq  = (const float*)d_in[9];
    const float* blq  = (const float*)d_in[10];
    const float* Wlk  = (const float*)d_in[11];
    const float* blk_ = (const float*)d_in[12];
    const float* Wlv  = (const float*)d_in[13];
    const float* blv  = (const float*)d_in[14];

    float* out   = (float*)d_out;
    float* ctx   = out;
    float* lctx  = out + (size_t)NB * SEQ * 768;
    float* probs = out + (size_t)NB * SEQ * 768 + (size_t)NB * SEQ * 192;

    char* ws = (char*)d_ws;
    unsigned short* Qc     = (unsigned short*)(ws);                 // 18,874,368 B
    unsigned short* Kc     = (unsigned short*)(ws + 18874368);      // 18,874,368 B
    unsigned short* VT     = (unsigned short*)(ws + 37748736);      // 15,728,640 B
    unsigned short* hid16  = (unsigned short*)(ws + 53477376);      // 12,582,912 B
    unsigned short* lay16  = (unsigned short*)(ws + 66060288);      //  3,145,728 B
    unsigned short* wqkv16 = (unsigned short*)(ws + 69206016);      //  3,538,944 B
    unsigned short* wl16   = (unsigned short*)(ws + 72744960);      //    221,184 B
    // total 72,966,144 B

    // bf16 conversions (weights packed into combined QKV / LQKV buffers)
    cvt_kernel<<<dim3(6144), dim3(256), 0, stream>>>(hs,  hid16, 1572864);
    cvt_kernel<<<dim3(1536), dim3(256), 0, stream>>>(lhs, lay16,  393216);
    cvt_kernel<<<dim3(576),  dim3(256), 0, stream>>>(Wq,  wqkv16,            147456);
    cvt_kernel<<<dim3(576),  dim3(256), 0, stream>>>(Wk,  wqkv16 +  589824,  147456);
    cvt_kernel<<<dim3(576),  dim3(256), 0, stream>>>(Wv,  wqkv16 + 1179648,  147456);
    cvt_kernel<<<dim3(36),   dim3(256), 0, stream>>>(Wlq, wl16,                9216);
    cvt_kernel<<<dim3(36),   dim3(256), 0, stream>>>(Wlk, wl16 + 36864,        9216);
    cvt_kernel<<<dim3(36),   dim3(256), 0, stream>>>(Wlv, wl16 + 73728,        9216);

    // fused projections (variant 1 writes the Qc/Kc zero pads — no memset needed)
    proj_gemm<<<dim3(64, 18), dim3(256), 0, stream>>>(hid16, wqkv16, bq, bk, bv,
                                                      Qc, Kc, VT, 768, 2304, 0);
    proj_gemm<<<dim3(64, 5),  dim3(256), 0, stream>>>(lay16, wl16, blq, blk_, blv,
                                                      Qc, Kc, VT, 192, 576, 1);

    // fused attention
    attn_kernel<<<dim3(1536), dim3(256), 0, stream>>>(Qc, Kc, VT, mask, ctx, lctx, probs);
}

// Round 4
// 371.873 us; speedup vs baseline: 1.0354x; 1.0354x over previous
//
#include <hip/hip_runtime.h>

#define NH   12
#define SEQ  1024
#define NB   8
#define DCAT 96
#define DV   80

typedef __attribute__((ext_vector_type(8))) short  bf16x8;
typedef __attribute__((ext_vector_type(4))) float  f32x4;
typedef __attribute__((ext_vector_type(4))) unsigned short u16x4;

static __device__ __forceinline__ unsigned short f2bf(float x) {
    unsigned int u = __float_as_uint(x);
    u += 0x7fffu + ((u >> 16) & 1u);   // RNE
    return (unsigned short)(u >> 16);
}
static __device__ __forceinline__ f32x4 fzero() {
    f32x4 z; z[0]=0.f; z[1]=0.f; z[2]=0.f; z[3]=0.f; return z;
}

#define GLDS16(gp, lp) __builtin_amdgcn_global_load_lds(                      \
    (const __attribute__((address_space(1))) void*)(gp),                      \
    (__attribute__((address_space(3))) void*)(lp), 16, 0, 0)

// ---------------- fused f32 -> bf16 convert (all 8 tensors, 1 launch) ----------------
__global__ __launch_bounds__(256) void cvt_all(
    const float* __restrict__ hs, const float* __restrict__ lhs,
    const float* __restrict__ Wq, const float* __restrict__ Wk, const float* __restrict__ Wv,
    const float* __restrict__ Wlq, const float* __restrict__ Wlk, const float* __restrict__ Wlv,
    unsigned short* __restrict__ hid16, unsigned short* __restrict__ lay16,
    unsigned short* __restrict__ wqkv16, unsigned short* __restrict__ wl16)
{
    int i = blockIdx.x * 256 + threadIdx.x;
    const float* src; unsigned short* dst; int off;
    if      (i < 1572864) { src = hs;  dst = hid16;           off = i; }
    else if (i < 1966080) { src = lhs; dst = lay16;           off = i - 1572864; }
    else if (i < 2113536) { src = Wq;  dst = wqkv16;          off = i - 1966080; }
    else if (i < 2260992) { src = Wk;  dst = wqkv16 + 589824; off = i - 2113536; }
    else if (i < 2408448) { src = Wv;  dst = wqkv16 + 1179648;off = i - 2260992; }
    else if (i < 2417664) { src = Wlq; dst = wl16;            off = i - 2408448; }
    else if (i < 2426880) { src = Wlk; dst = wl16 + 36864;    off = i - 2417664; }
    else if (i < 2436096) { src = Wlv; dst = wl16 + 73728;    off = i - 2426880; }
    else return;
    f32x4 v = ((const f32x4*)src)[off];
    u16x4 o;
    o[0] = f2bf(v[0]); o[1] = f2bf(v[1]); o[2] = f2bf(v[2]); o[3] = f2bf(v[3]);
    ((u16x4*)dst)[off] = o;
}

// ---------------- fused projection GEMM ----------------
// C[8192, Ntot] = A[8192,K] @ Bw[Ntot,K]^T, epilogue scatters into Qc/Kc/VT.
// variant 0: Ntot=2304 (Q|K|V, seg 768), variant 1: Ntot=576 (LQ|LK|LV, seg 192)
// variant 1 also writes the d=80..95 zero pad of Qc/Kc (replaces memset).
__global__ __launch_bounds__(256) void proj_gemm(
    const unsigned short* __restrict__ A,
    const unsigned short* __restrict__ Bw,
    const float* __restrict__ b0, const float* __restrict__ b1, const float* __restrict__ b2,
    unsigned short* __restrict__ Qc, unsigned short* __restrict__ Kc, unsigned short* __restrict__ VT,
    int K, int Ntot, int variant)
{
    __shared__ __align__(16) unsigned short As[4096];   // [128][32]
    __shared__ __align__(16) unsigned short Bs[4096];   // [128][32]
    const int tid = threadIdx.x, w = tid >> 6, lane = tid & 63;
    const int g = lane >> 4, c = lane & 15;
    const int m0 = blockIdx.x * 128, n0 = blockIdx.y * 128;
    const int wr = w >> 1, wc = w & 1;
    const int srow = lane >> 2, scol = (lane & 3) * 8;

    f32x4 acc[4][4];
    #pragma unroll
    for (int m = 0; m < 4; m++)
        #pragma unroll
        for (int n = 0; n < 4; n++) acc[m][n] = fzero();

    const int ch0 = w * 2, ch1 = w * 2 + 1;
    const size_t arow0 = (size_t)(m0 + ch0 * 16 + srow) * K + scol;
    const size_t arow1 = (size_t)(m0 + ch1 * 16 + srow) * K + scol;
    int bn0 = n0 + ch0 * 16 + srow; if (bn0 >= Ntot) bn0 = Ntot - 1;
    int bn1 = n0 + ch1 * 16 + srow; if (bn1 >= Ntot) bn1 = Ntot - 1;
    const size_t brow0 = (size_t)bn0 * K + scol;
    const size_t brow1 = (size_t)bn1 * K + scol;

    for (int k0 = 0; k0 < K; k0 += 32) {
        __syncthreads();
        GLDS16(A  + arow0 + k0, As + ch0 * 512);
        GLDS16(A  + arow1 + k0, As + ch1 * 512);
        GLDS16(Bw + brow0 + k0, Bs + ch0 * 512);
        GLDS16(Bw + brow1 + k0, Bs + ch1 * 512);
        __syncthreads();
        bf16x8 af[4], bfr[4];
        #pragma unroll
        for (int m = 0; m < 4; m++) af[m]  = *(const bf16x8*)&As[(wr*64 + m*16 + c)*32 + g*8];
        #pragma unroll
        for (int n = 0; n < 4; n++) bfr[n] = *(const bf16x8*)&Bs[(wc*64 + n*16 + c)*32 + g*8];
        #pragma unroll
        for (int m = 0; m < 4; m++)
            #pragma unroll
            for (int n = 0; n < 4; n++)
                acc[m][n] = __builtin_amdgcn_mfma_f32_16x16x32_bf16(af[m], bfr[n], acc[m][n], 0, 0, 0);
    }

    // epilogue: scatter with bias + scale into head layouts
    const int b_ = m0 >> 10;
    #pragma unroll
    for (int nf = 0; nf < 4; nf++) {
        int n = n0 + wc * 64 + nf * 16 + c;
        if (n >= Ntot) continue;
        int seg, nn;
        if (variant == 0) { seg = (n >= 1536) ? 2 : ((n >= 768) ? 1 : 0); nn = n - seg * 768; }
        else              { seg = (n >= 384)  ? 2 : ((n >= 192) ? 1 : 0); nn = n - seg * 192; }
        const float* bp = (seg == 0) ? b0 : ((seg == 1) ? b1 : b2);
        float bv = bp[nn];
        float scale = (seg == 0) ? (variant ? 0.25f : 0.125f) : 1.0f;
        int h, d;
        if (variant == 0) { h = nn >> 6; d = nn & 63; }
        else              { h = nn >> 4; d = 64 + (nn & 15); }
        #pragma unroll
        for (int m = 0; m < 4; m++) {
            int row = m0 + wr * 64 + m * 16 + 4 * g;
            int s = row & 1023;
            if (seg < 2) {
                unsigned short* dst = (seg == 0) ? Qc : Kc;
                size_t base = (size_t)(b_ * NH + h) * SEQ;
                #pragma unroll
                for (int r = 0; r < 4; r++) {
                    dst[(base + s + r) * DCAT + d] = f2bf((acc[m][nf][r] + bv) * scale);
                    if (variant == 1)
                        dst[(base + s + r) * DCAT + d + 16] = 0;   // zero pad d=80..95
                }
            } else {
                u16x4 pk;
                #pragma unroll
                for (int r = 0; r < 4; r++) pk[r] = f2bf(acc[m][nf][r] + bv);
                *(u16x4*)&VT[((size_t)(b_ * NH + h) * DV + d) * SEQ + s] = pk;
            }
        }
    }
}

// ---------------- fused attention: 2-pass max-free softmax, barrier-free ----------------
// grid: 1536 blocks (XCD-swizzled so each bh's 16 q-tiles share one XCD's L2).
// 4 waves/block, each owns 16 q rows, fully independent (no __syncthreads).
// K/V fragments read directly from global (L2-resident thanks to swizzle).
__global__ __launch_bounds__(256) void attn_kernel(
    const unsigned short* __restrict__ Qc,   // [BH, SEQ, 96] bf16: q/8 | lq/4 | 0
    const unsigned short* __restrict__ Kc,   // [BH, SEQ, 96] bf16: k | lk | 0
    const unsigned short* __restrict__ VT,   // [BH, 80, SEQ] bf16 (d-major)
    const float* __restrict__ mask,          // [NB, SEQ]
    float* __restrict__ ctx,                 // [NB, SEQ, 768]
    float* __restrict__ lctx,                // [NB, SEQ, 192]
    float* __restrict__ probs)               // [BH, SEQ, SEQ]
{
    __shared__ __align__(16) float sbuf[4][16][36];   // per-wave P transpose buffer

    const int tid = threadIdx.x, w = tid >> 6, lane = tid & 63;
    const int g = lane >> 4, c = lane & 15;

    // XCD-bijective swizzle: all 16 q-tiles of one bh land on one XCD
    const int bid = blockIdx.x;
    const int xc = bid & 7, j = bid >> 3;     // j in 0..191
    const int bh = xc + 8 * (j >> 4);         // 0..95
    const int qt = j & 15;
    const int b = bh / NH, h = bh % NH;
    const int qrb = qt * 64 + w * 16;
    const float NEGF = -3.4028234663852886e38f;

    bf16x8 qf0, qf1, qf2;
    {
        const unsigned short* qrow = &Qc[((size_t)bh * SEQ + qrb + c) * DCAT + g * 8];
        qf0 = *(const bf16x8*)(qrow);
        qf1 = *(const bf16x8*)(qrow + 32);
        qf2 = *(const bf16x8*)(qrow + 64);
    }
    const unsigned short* Kb = Kc + (size_t)bh * SEQ * DCAT + g * 8;
    const unsigned short* Vb = VT + (size_t)bh * DV * SEQ;
    const float* mk = mask + b * SEQ;

    // ---- pass A: per-lane partial sum of exp(s) (no max: |s| small) ----
    float sm[4] = {0.f, 0.f, 0.f, 0.f};
    #pragma unroll 2
    for (int kt = 0; kt < 64; kt++) {
        const unsigned short* kr = Kb + (size_t)(kt * 16 + c) * DCAT;
        bf16x8 k0 = *(const bf16x8*)(kr);
        bf16x8 k1 = *(const bf16x8*)(kr + 32);
        bf16x8 k2 = *(const bf16x8*)(kr + 64);
        float bias = (1.0f - mk[kt * 16 + c]) * NEGF;
        __builtin_amdgcn_s_setprio(1);
        f32x4 a = fzero();
        a = __builtin_amdgcn_mfma_f32_16x16x32_bf16(qf0, k0, a, 0, 0, 0);
        a = __builtin_amdgcn_mfma_f32_16x16x32_bf16(qf1, k1, a, 0, 0, 0);
        a = __builtin_amdgcn_mfma_f32_16x16x32_bf16(qf2, k2, a, 0, 0, 0);
        __builtin_amdgcn_s_setprio(0);
        #pragma unroll
        for (int r = 0; r < 4; r++) sm[r] += __expf(a[r] + bias);
    }
    #pragma unroll
    for (int off = 8; off >= 1; off >>= 1)
        #pragma unroll
        for (int r = 0; r < 4; r++) sm[r] += __shfl_xor(sm[r], off);
    float rinv[4];
    #pragma unroll
    for (int r = 0; r < 4; r++) rinv[r] = 1.0f / fmaxf(sm[r], 1e-38f);

    // ---- pass B: recompute scores, write probs (coalesced), PV accumulate ----
    f32x4 cacc[5];
    #pragma unroll
    for (int nf = 0; nf < 5; nf++) cacc[nf] = fzero();

    const int prow = lane >> 3, pcb = lane & 7;
    const size_t pbase = ((size_t)bh * SEQ + qrb) * SEQ;

    for (int kp = 0; kp < 32; kp++) {
        #pragma unroll
        for (int ph = 0; ph < 2; ph++) {
            int kt = kp * 2 + ph;
            const unsigned short* kr = Kb + (size_t)(kt * 16 + c) * DCAT;
            bf16x8 k0 = *(const bf16x8*)(kr);
            bf16x8 k1 = *(const bf16x8*)(kr + 32);
            bf16x8 k2 = *(const bf16x8*)(kr + 64);
            float bias = (1.0f - mk[kt * 16 + c]) * NEGF;
            __builtin_amdgcn_s_setprio(1);
            f32x4 a = fzero();
            a = __builtin_amdgcn_mfma_f32_16x16x32_bf16(qf0, k0, a, 0, 0, 0);
            a = __builtin_amdgcn_mfma_f32_16x16x32_bf16(qf1, k1, a, 0, 0, 0);
            a = __builtin_amdgcn_mfma_f32_16x16x32_bf16(qf2, k2, a, 0, 0, 0);
            __builtin_amdgcn_s_setprio(0);
            #pragma unroll
            for (int r = 0; r < 4; r++)
                sbuf[w][4 * g + r][ph * 16 + c] = __expf(a[r] + bias) * rinv[r];
        }
        // coalesced probs store: lanes 0..7 cover one full 128B row segment
        f32x4 pv0 = *(const f32x4*)&sbuf[w][prow][pcb * 4];
        f32x4 pv1 = *(const f32x4*)&sbuf[w][8 + prow][pcb * 4];
        *(f32x4*)&probs[pbase + (size_t)prow * SEQ + kp * 32 + pcb * 4] = pv0;
        *(f32x4*)&probs[pbase + (size_t)(8 + prow) * SEQ + kp * 32 + pcb * 4] = pv1;

        // PV A-fragment from sbuf (row = q, cols = k-chunk)
        f32x4 pa0 = *(const f32x4*)&sbuf[w][c][g * 8];
        f32x4 pa1 = *(const f32x4*)&sbuf[w][c][g * 8 + 4];
        bf16x8 pa;
        #pragma unroll
        for (int jj = 0; jj < 4; jj++) { pa[jj] = (short)f2bf(pa0[jj]); pa[4 + jj] = (short)f2bf(pa1[jj]); }
        __builtin_amdgcn_s_setprio(1);
        #pragma unroll
        for (int nf = 0; nf < 5; nf++) {
            bf16x8 vf = *(const bf16x8*)&Vb[(size_t)(nf * 16 + c) * SEQ + kp * 32 + g * 8];
            cacc[nf] = __builtin_amdgcn_mfma_f32_16x16x32_bf16(pa, vf, cacc[nf], 0, 0, 0);
        }
        __builtin_amdgcn_s_setprio(0);
    }

    // ---- epilogue ----
    #pragma unroll
    for (int nf = 0; nf < 4; nf++)
        #pragma unroll
        for (int r = 0; r < 4; r++) {
            int q = qrb + 4 * g + r;
            ctx[((size_t)(b * SEQ + q)) * 768 + h * 64 + nf * 16 + c] = cacc[nf][r];
        }
    #pragma unroll
    for (int r = 0; r < 4; r++) {
        int q = qrb + 4 * g + r;
        lctx[((size_t)(b * SEQ + q)) * 192 + h * 16 + c] = cacc[4][r];
    }
}

// ---------------- host launch ----------------
extern "C" void kernel_launch(void* const* d_in, const int* in_sizes, int n_in,
                              void* d_out, int out_size, void* d_ws, size_t ws_size,
                              hipStream_t stream)
{
    const float* hs   = (const float*)d_in[0];
    const float* lhs  = (const float*)d_in[1];
    const float* mask = (const float*)d_in[2];
    const float* Wq   = (const float*)d_in[3];
    const float* bq   = (const float*)d_in[4];
    const float* Wk   = (const float*)d_in[5];
    const float* bk   = (const float*)d_in[6];
    const float* Wv   = (const float*)d_in[7];
    const float* bv   = (const float*)d_in[8];
    const float* Wlq  = (const float*)d_in[9];
    const float* blq  = (const float*)d_in[10];
    const float* Wlk  = (const float*)d_in[11];
    const float* blk_ = (const float*)d_in[12];
    const float* Wlv  = (const float*)d_in[13];
    const float* blv  = (const float*)d_in[14];

    float* out   = (float*)d_out;
    float* ctx   = out;
    float* lctx  = out + (size_t)NB * SEQ * 768;
    float* probs = out + (size_t)NB * SEQ * 768 + (size_t)NB * SEQ * 192;

    char* ws = (char*)d_ws;
    unsigned short* Qc     = (unsigned short*)(ws);                 // 18,874,368 B
    unsigned short* Kc     = (unsigned short*)(ws + 18874368);      // 18,874,368 B
    unsigned short* VT     = (unsigned short*)(ws + 37748736);      // 15,728,640 B
    unsigned short* hid16  = (unsigned short*)(ws + 53477376);      // 12,582,912 B
    unsigned short* lay16  = (unsigned short*)(ws + 66060288);      //  3,145,728 B
    unsigned short* wqkv16 = (unsigned short*)(ws + 69206016);      //  3,538,944 B
    unsigned short* wl16   = (unsigned short*)(ws + 72744960);      //    221,184 B
    // total 72,966,144 B

    // one fused bf16 conversion launch (8 tensors)
    cvt_all<<<dim3(9516), dim3(256), 0, stream>>>(hs, lhs, Wq, Wk, Wv, Wlq, Wlk, Wlv,
                                                  hid16, lay16, wqkv16, wl16);

    // fused projections (variant 1 writes the Qc/Kc zero pads — no memset needed)
    proj_gemm<<<dim3(64, 18), dim3(256), 0, stream>>>(hid16, wqkv16, bq, bk, bv,
                                                      Qc, Kc, VT, 768, 2304, 0);
    proj_gemm<<<dim3(64, 5),  dim3(256), 0, stream>>>(lay16, wl16, blq, blk_, blv,
                                                      Qc, Kc, VT, 192, 576, 1);

    // fused attention
    attn_kernel<<<dim3(1536), dim3(256), 0, stream>>>(Qc, Kc, VT, mask, ctx, lctx, probs);
}

// Round 5
// 303.501 us; speedup vs baseline: 1.2687x; 1.2253x over previous
//
#include <hip/hip_runtime.h>

#define NH   12
#define SEQ  1024
#define NB   8
#define DCAT 96
#define DV   80

typedef __attribute__((ext_vector_type(8))) short  bf16x8;
typedef __attribute__((ext_vector_type(4))) float  f32x4;
typedef __attribute__((ext_vector_type(4))) unsigned short u16x4;

static __device__ __forceinline__ unsigned short f2bf(float x) {
    unsigned int u = __float_as_uint(x);
    u += 0x7fffu + ((u >> 16) & 1u);   // RNE
    return (unsigned short)(u >> 16);
}
static __device__ __forceinline__ f32x4 fzero() {
    f32x4 z; z[0]=0.f; z[1]=0.f; z[2]=0.f; z[3]=0.f; return z;
}

#define GLDS16(gp, lp) __builtin_amdgcn_global_load_lds(                      \
    (const __attribute__((address_space(1))) void*)(gp),                      \
    (__attribute__((address_space(3))) void*)(lp), 16, 0, 0)

// ---------------- fused f32 -> bf16 convert (all 8 tensors, 1 launch) ----------------
__global__ __launch_bounds__(256) void cvt_all(
    const float* __restrict__ hs, const float* __restrict__ lhs,
    const float* __restrict__ Wq, const float* __restrict__ Wk, const float* __restrict__ Wv,
    const float* __restrict__ Wlq, const float* __restrict__ Wlk, const float* __restrict__ Wlv,
    unsigned short* __restrict__ hid16, unsigned short* __restrict__ lay16,
    unsigned short* __restrict__ wqkv16, unsigned short* __restrict__ wl16)
{
    int i = blockIdx.x * 256 + threadIdx.x;
    const float* src; unsigned short* dst; int off;
    if      (i < 1572864) { src = hs;  dst = hid16;           off = i; }
    else if (i < 1966080) { src = lhs; dst = lay16;           off = i - 1572864; }
    else if (i < 2113536) { src = Wq;  dst = wqkv16;          off = i - 1966080; }
    else if (i < 2260992) { src = Wk;  dst = wqkv16 + 589824; off = i - 2113536; }
    else if (i < 2408448) { src = Wv;  dst = wqkv16 + 1179648;off = i - 2260992; }
    else if (i < 2417664) { src = Wlq; dst = wl16;            off = i - 2408448; }
    else if (i < 2426880) { src = Wlk; dst = wl16 + 36864;    off = i - 2417664; }
    else if (i < 2436096) { src = Wlv; dst = wl16 + 73728;    off = i - 2426880; }
    else return;
    f32x4 v = ((const f32x4*)src)[off];
    u16x4 o;
    o[0] = f2bf(v[0]); o[1] = f2bf(v[1]); o[2] = f2bf(v[2]); o[3] = f2bf(v[3]);
    ((u16x4*)dst)[off] = o;
}

// ---------------- fused projection GEMM ----------------
__global__ __launch_bounds__(256) void proj_gemm(
    const unsigned short* __restrict__ A,
    const unsigned short* __restrict__ Bw,
    const float* __restrict__ b0, const float* __restrict__ b1, const float* __restrict__ b2,
    unsigned short* __restrict__ Qc, unsigned short* __restrict__ Kc, unsigned short* __restrict__ VT,
    int K, int Ntot, int variant)
{
    __shared__ __align__(16) unsigned short As[4096];   // [128][32]
    __shared__ __align__(16) unsigned short Bs[4096];   // [128][32]
    const int tid = threadIdx.x, w = tid >> 6, lane = tid & 63;
    const int g = lane >> 4, c = lane & 15;
    const int m0 = blockIdx.x * 128, n0 = blockIdx.y * 128;
    const int wr = w >> 1, wc = w & 1;
    const int srow = lane >> 2, scol = (lane & 3) * 8;

    f32x4 acc[4][4];
    #pragma unroll
    for (int m = 0; m < 4; m++)
        #pragma unroll
        for (int n = 0; n < 4; n++) acc[m][n] = fzero();

    const int ch0 = w * 2, ch1 = w * 2 + 1;
    const size_t arow0 = (size_t)(m0 + ch0 * 16 + srow) * K + scol;
    const size_t arow1 = (size_t)(m0 + ch1 * 16 + srow) * K + scol;
    int bn0 = n0 + ch0 * 16 + srow; if (bn0 >= Ntot) bn0 = Ntot - 1;
    int bn1 = n0 + ch1 * 16 + srow; if (bn1 >= Ntot) bn1 = Ntot - 1;
    const size_t brow0 = (size_t)bn0 * K + scol;
    const size_t brow1 = (size_t)bn1 * K + scol;

    for (int k0 = 0; k0 < K; k0 += 32) {
        __syncthreads();
        GLDS16(A  + arow0 + k0, As + ch0 * 512);
        GLDS16(A  + arow1 + k0, As + ch1 * 512);
        GLDS16(Bw + brow0 + k0, Bs + ch0 * 512);
        GLDS16(Bw + brow1 + k0, Bs + ch1 * 512);
        __syncthreads();
        bf16x8 af[4], bfr[4];
        #pragma unroll
        for (int m = 0; m < 4; m++) af[m]  = *(const bf16x8*)&As[(wr*64 + m*16 + c)*32 + g*8];
        #pragma unroll
        for (int n = 0; n < 4; n++) bfr[n] = *(const bf16x8*)&Bs[(wc*64 + n*16 + c)*32 + g*8];
        #pragma unroll
        for (int m = 0; m < 4; m++)
            #pragma unroll
            for (int n = 0; n < 4; n++)
                acc[m][n] = __builtin_amdgcn_mfma_f32_16x16x32_bf16(af[m], bfr[n], acc[m][n], 0, 0, 0);
    }

    const int b_ = m0 >> 10;
    #pragma unroll
    for (int nf = 0; nf < 4; nf++) {
        int n = n0 + wc * 64 + nf * 16 + c;
        if (n >= Ntot) continue;
        int seg, nn;
        if (variant == 0) { seg = (n >= 1536) ? 2 : ((n >= 768) ? 1 : 0); nn = n - seg * 768; }
        else              { seg = (n >= 384)  ? 2 : ((n >= 192) ? 1 : 0); nn = n - seg * 192; }
        const float* bp = (seg == 0) ? b0 : ((seg == 1) ? b1 : b2);
        float bv = bp[nn];
        float scale = (seg == 0) ? (variant ? 0.25f : 0.125f) : 1.0f;
        int h, d;
        if (variant == 0) { h = nn >> 6; d = nn & 63; }
        else              { h = nn >> 4; d = 64 + (nn & 15); }
        #pragma unroll
        for (int m = 0; m < 4; m++) {
            int row = m0 + wr * 64 + m * 16 + 4 * g;
            int s = row & 1023;
            if (seg < 2) {
                unsigned short* dst = (seg == 0) ? Qc : Kc;
                size_t base = (size_t)(b_ * NH + h) * SEQ;
                #pragma unroll
                for (int r = 0; r < 4; r++) {
                    dst[(base + s + r) * DCAT + d] = f2bf((acc[m][nf][r] + bv) * scale);
                    if (variant == 1)
                        dst[(base + s + r) * DCAT + d + 16] = 0;   // zero pad d=80..95
                }
            } else {
                u16x4 pk;
                #pragma unroll
                for (int r = 0; r < 4; r++) pk[r] = f2bf(acc[m][nf][r] + bv);
                *(u16x4*)&VT[((size_t)(b_ * NH + h) * DV + d) * SEQ + s] = pk;
            }
        }
    }
}

// ---------------- fused attention: swapped-operand, 2 q-tiles/wave ----------------
// grid: 768 blocks (XCD-swizzled, 8 q-tiles x 12 bh per XCD). 4 waves/block,
// each wave owns 32 q rows (2 MFMA column-tiles), no barriers.
// mfma(K,Q) => lane(g,c) holds P[k=kt*16+4g+r][q=qrb(+16)+c]:
//   probs store = direct per-lane f32x4; softmax sum = per-lane scalar.
__global__ __launch_bounds__(256, 3) void attn_kernel(
    const unsigned short* __restrict__ Qc,   // [BH, SEQ, 96] bf16: q/8 | lq/4 | 0
    const unsigned short* __restrict__ Kc,   // [BH, SEQ, 96] bf16: k | lk | 0
    const unsigned short* __restrict__ VT,   // [BH, 80, SEQ] bf16 (d-major)
    const float* __restrict__ mask,          // [NB, SEQ]
    float* __restrict__ ctx,                 // [NB, SEQ, 768]
    float* __restrict__ lctx,                // [NB, SEQ, 192]
    float* __restrict__ probs)               // [BH, SEQ, SEQ]
{
    __shared__ __align__(16) unsigned short pbuf[4][32][36];  // [wave][q-local][k-local]

    const int tid = threadIdx.x, w = tid >> 6, lane = tid & 63;
    const int g = lane >> 4, c = lane & 15;

    // XCD-bijective swizzle: 8 q-tiles of one bh land consecutively on one XCD
    const int bid = blockIdx.x;
    const int xc = bid & 7, j = bid >> 3;     // j in 0..95
    const int bh = xc + 8 * (j >> 3);         // 0..95
    const int qt = j & 7;
    const int b = bh / NH, h = bh % NH;
    const int qrb = qt * 128 + w * 32;        // this wave's 32 q rows
    const float NEGF = -3.4028234663852886e38f;

    // Q fragments for both q-tiles (B-operand of swapped QK^T)
    bf16x8 qa0, qa1, qa2, qb0, qb1, qb2;
    {
        const unsigned short* qr0 = &Qc[((size_t)bh * SEQ + qrb + c) * DCAT + g * 8];
        qa0 = *(const bf16x8*)(qr0);
        qa1 = *(const bf16x8*)(qr0 + 32);
        qa2 = *(const bf16x8*)(qr0 + 64);
        const unsigned short* qr1 = qr0 + 16 * DCAT;
        qb0 = *(const bf16x8*)(qr1);
        qb1 = *(const bf16x8*)(qr1 + 32);
        qb2 = *(const bf16x8*)(qr1 + 64);
    }
    const unsigned short* Kb = Kc + (size_t)bh * SEQ * DCAT + g * 8;
    const unsigned short* Vb = VT + (size_t)bh * DV * SEQ;
    const float* mk = mask + b * SEQ;

    // ---- pass A: per-lane scalar partial sums of exp(s) ----
    float sm0 = 0.f, sm1 = 0.f;
    for (int kt = 0; kt < 64; kt++) {
        const unsigned short* kr = Kb + (size_t)(kt * 16 + c) * DCAT;
        bf16x8 k0 = *(const bf16x8*)(kr);
        bf16x8 k1 = *(const bf16x8*)(kr + 32);
        bf16x8 k2 = *(const bf16x8*)(kr + 64);
        f32x4 m4 = *(const f32x4*)&mk[kt * 16 + 4 * g];
        __builtin_amdgcn_s_setprio(1);
        f32x4 a0 = __builtin_amdgcn_mfma_f32_16x16x32_bf16(k0, qa0, fzero(), 0, 0, 0);
        f32x4 a1 = __builtin_amdgcn_mfma_f32_16x16x32_bf16(k1, qa1, fzero(), 0, 0, 0);
        f32x4 a2 = __builtin_amdgcn_mfma_f32_16x16x32_bf16(k2, qa2, fzero(), 0, 0, 0);
        f32x4 b0 = __builtin_amdgcn_mfma_f32_16x16x32_bf16(k0, qb0, fzero(), 0, 0, 0);
        f32x4 b1 = __builtin_amdgcn_mfma_f32_16x16x32_bf16(k1, qb1, fzero(), 0, 0, 0);
        f32x4 b2 = __builtin_amdgcn_mfma_f32_16x16x32_bf16(k2, qb2, fzero(), 0, 0, 0);
        __builtin_amdgcn_s_setprio(0);
        #pragma unroll
        for (int r = 0; r < 4; r++) {
            float bias = (1.0f - m4[r]) * NEGF;
            sm0 += __expf(a0[r] + a1[r] + a2[r] + bias);
            sm1 += __expf(b0[r] + b1[r] + b2[r] + bias);
        }
    }
    sm0 += __shfl_xor(sm0, 16); sm0 += __shfl_xor(sm0, 32);
    sm1 += __shfl_xor(sm1, 16); sm1 += __shfl_xor(sm1, 32);
    const float rinv0 = 1.0f / fmaxf(sm0, 1e-38f);
    const float rinv1 = 1.0f / fmaxf(sm1, 1e-38f);

    // ---- pass B: recompute, direct probs stores, PV accumulate ----
    f32x4 cacc0[5], cacc1[5];
    #pragma unroll
    for (int nf = 0; nf < 5; nf++) { cacc0[nf] = fzero(); cacc1[nf] = fzero(); }

    const size_t prow0 = ((size_t)bh * SEQ + qrb + c) * SEQ;
    const size_t prow1 = prow0 + 16 * SEQ;

    for (int kp = 0; kp < 32; kp++) {
        #pragma unroll
        for (int ph = 0; ph < 2; ph++) {
            const int kt = kp * 2 + ph;
            const unsigned short* kr = Kb + (size_t)(kt * 16 + c) * DCAT;
            bf16x8 k0 = *(const bf16x8*)(kr);
            bf16x8 k1 = *(const bf16x8*)(kr + 32);
            bf16x8 k2 = *(const bf16x8*)(kr + 64);
            f32x4 m4 = *(const f32x4*)&mk[kt * 16 + 4 * g];
            __builtin_amdgcn_s_setprio(1);
            f32x4 a0 = __builtin_amdgcn_mfma_f32_16x16x32_bf16(k0, qa0, fzero(), 0, 0, 0);
            f32x4 a1 = __builtin_amdgcn_mfma_f32_16x16x32_bf16(k1, qa1, fzero(), 0, 0, 0);
            f32x4 a2 = __builtin_amdgcn_mfma_f32_16x16x32_bf16(k2, qa2, fzero(), 0, 0, 0);
            f32x4 b0 = __builtin_amdgcn_mfma_f32_16x16x32_bf16(k0, qb0, fzero(), 0, 0, 0);
            f32x4 b1 = __builtin_amdgcn_mfma_f32_16x16x32_bf16(k1, qb1, fzero(), 0, 0, 0);
            f32x4 b2 = __builtin_amdgcn_mfma_f32_16x16x32_bf16(k2, qb2, fzero(), 0, 0, 0);
            __builtin_amdgcn_s_setprio(0);
            f32x4 p0, p1;
            u16x4 h0, h1;
            #pragma unroll
            for (int r = 0; r < 4; r++) {
                float bias = (1.0f - m4[r]) * NEGF;
                p0[r] = __expf(a0[r] + a1[r] + a2[r] + bias) * rinv0;
                p1[r] = __expf(b0[r] + b1[r] + b2[r] + bias) * rinv1;
                h0[r] = f2bf(p0[r]);
                h1[r] = f2bf(p1[r]);
            }
            // direct per-lane coalesced probs stores (rows q=qrb+c, qrb+16+c)
            *(f32x4*)&probs[prow0 + kt * 16 + 4 * g] = p0;
            *(f32x4*)&probs[prow1 + kt * 16 + 4 * g] = p1;
            // PV staging: pbuf[q-local][k-local]
            *(u16x4*)&pbuf[w][c][ph * 16 + 4 * g]      = h0;
            *(u16x4*)&pbuf[w][16 + c][ph * 16 + 4 * g] = h1;
        }
        bf16x8 pa0 = *(const bf16x8*)&pbuf[w][c][g * 8];
        bf16x8 pa1 = *(const bf16x8*)&pbuf[w][16 + c][g * 8];
        __builtin_amdgcn_s_setprio(1);
        #pragma unroll
        for (int nf = 0; nf < 5; nf++) {
            bf16x8 vf = *(const bf16x8*)&Vb[(size_t)(nf * 16 + c) * SEQ + kp * 32 + g * 8];
            cacc0[nf] = __builtin_amdgcn_mfma_f32_16x16x32_bf16(pa0, vf, cacc0[nf], 0, 0, 0);
            cacc1[nf] = __builtin_amdgcn_mfma_f32_16x16x32_bf16(pa1, vf, cacc1[nf], 0, 0, 0);
        }
        __builtin_amdgcn_s_setprio(0);
    }

    // ---- epilogue ----
    #pragma unroll
    for (int nf = 0; nf < 4; nf++)
        #pragma unroll
        for (int r = 0; r < 4; r++) {
            int q0 = qrb + 4 * g + r;
            ctx[((size_t)(b * SEQ + q0)) * 768 + h * 64 + nf * 16 + c] = cacc0[nf][r];
            ctx[((size_t)(b * SEQ + q0 + 16)) * 768 + h * 64 + nf * 16 + c] = cacc1[nf][r];
        }
    #pragma unroll
    for (int r = 0; r < 4; r++) {
        int q0 = qrb + 4 * g + r;
        lctx[((size_t)(b * SEQ + q0)) * 192 + h * 16 + c] = cacc0[4][r];
        lctx[((size_t)(b * SEQ + q0 + 16)) * 192 + h * 16 + c] = cacc1[4][r];
    }
}

// ---------------- host launch ----------------
extern "C" void kernel_launch(void* const* d_in, const int* in_sizes, int n_in,
                              void* d_out, int out_size, void* d_ws, size_t ws_size,
                              hipStream_t stream)
{
    const float* hs   = (const float*)d_in[0];
    const float* lhs  = (const float*)d_in[1];
    const float* mask = (const float*)d_in[2];
    const float* Wq   = (const float*)d_in[3];
    const float* bq   = (const float*)d_in[4];
    const float* Wk   = (const float*)d_in[5];
    const float* bk   = (const float*)d_in[6];
    const float* Wv   = (const float*)d_in[7];
    const float* bv   = (const float*)d_in[8];
    const float* Wlq  = (const float*)d_in[9];
    const float* blq  = (const float*)d_in[10];
    const float* Wlk  = (const float*)d_in[11];
    const float* blk_ = (const float*)d_in[12];
    const float* Wlv  = (const float*)d_in[13];
    const float* blv  = (const float*)d_in[14];

    float* out   = (float*)d_out;
    float* ctx   = out;
    float* lctx  = out + (size_t)NB * SEQ * 768;
    float* probs = out + (size_t)NB * SEQ * 768 + (size_t)NB * SEQ * 192;

    char* ws = (char*)d_ws;
    unsigned short* Qc     = (unsigned short*)(ws);                 // 18,874,368 B
    unsigned short* Kc     = (unsigned short*)(ws + 18874368);      // 18,874,368 B
    unsigned short* VT     = (unsigned short*)(ws + 37748736);      // 15,728,640 B
    unsigned short* hid16  = (unsigned short*)(ws + 53477376);      // 12,582,912 B
    unsigned short* lay16  = (unsigned short*)(ws + 66060288);      //  3,145,728 B
    unsigned short* wqkv16 = (unsigned short*)(ws + 69206016);      //  3,538,944 B
    unsigned short* wl16   = (unsigned short*)(ws + 72744960);      //    221,184 B

    // one fused bf16 conversion launch (8 tensors)
    cvt_all<<<dim3(9516), dim3(256), 0, stream>>>(hs, lhs, Wq, Wk, Wv, Wlq, Wlk, Wlv,
                                                  hid16, lay16, wqkv16, wl16);

    // fused projections (variant 1 writes the Qc/Kc zero pads — no memset needed)
    proj_gemm<<<dim3(64, 18), dim3(256), 0, stream>>>(hid16, wqkv16, bq, bk, bv,
                                                      Qc, Kc, VT, 768, 2304, 0);
    proj_gemm<<<dim3(64, 5),  dim3(256), 0, stream>>>(lay16, wl16, blq, blk_, blv,
                                                      Qc, Kc, VT, 192, 576, 1);

    // fused attention
    attn_kernel<<<dim3(768), dim3(256), 0, stream>>>(Qc, Kc, VT, mask, ctx, lctx, probs);
}

// Round 6
// 247.367 us; speedup vs baseline: 1.5565x; 1.2269x over previous
//
#include <hip/hip_runtime.h>

#define NH   12
#define SEQ  1024
#define NB   8
#define DCAT 96
#define DV   80

typedef __attribute__((ext_vector_type(8))) short  bf16x8;
typedef __attribute__((ext_vector_type(4))) float  f32x4;
typedef __attribute__((ext_vector_type(4))) unsigned short u16x4;

static __device__ __forceinline__ unsigned short f2bf(float x) {
    unsigned int u = __float_as_uint(x);
    u += 0x7fffu + ((u >> 16) & 1u);   // RNE
    return (unsigned short)(u >> 16);
}
static __device__ __forceinline__ f32x4 fzero() {
    f32x4 z; z[0]=0.f; z[1]=0.f; z[2]=0.f; z[3]=0.f; return z;
}

#define GLDS16(gp, lp) __builtin_amdgcn_global_load_lds(                      \
    (const __attribute__((address_space(1))) void*)(gp),                      \
    (__attribute__((address_space(3))) void*)(lp), 16, 0, 0)

// ---------------- fused f32 -> bf16 convert (all 8 tensors, 1 launch) ----------------
__global__ __launch_bounds__(256) void cvt_all(
    const float* __restrict__ hs, const float* __restrict__ lhs,
    const float* __restrict__ Wq, const float* __restrict__ Wk, const float* __restrict__ Wv,
    const float* __restrict__ Wlq, const float* __restrict__ Wlk, const float* __restrict__ Wlv,
    unsigned short* __restrict__ hid16, unsigned short* __restrict__ lay16,
    unsigned short* __restrict__ wqkv16, unsigned short* __restrict__ wl16)
{
    int i = blockIdx.x * 256 + threadIdx.x;
    const float* src; unsigned short* dst; int off;
    if      (i < 1572864) { src = hs;  dst = hid16;           off = i; }
    else if (i < 1966080) { src = lhs; dst = lay16;           off = i - 1572864; }
    else if (i < 2113536) { src = Wq;  dst = wqkv16;          off = i - 1966080; }
    else if (i < 2260992) { src = Wk;  dst = wqkv16 + 589824; off = i - 2113536; }
    else if (i < 2408448) { src = Wv;  dst = wqkv16 + 1179648;off = i - 2260992; }
    else if (i < 2417664) { src = Wlq; dst = wl16;            off = i - 2408448; }
    else if (i < 2426880) { src = Wlk; dst = wl16 + 36864;    off = i - 2417664; }
    else if (i < 2436096) { src = Wlv; dst = wl16 + 73728;    off = i - 2426880; }
    else return;
    f32x4 v = ((const f32x4*)src)[off];
    u16x4 o;
    o[0] = f2bf(v[0]); o[1] = f2bf(v[1]); o[2] = f2bf(v[2]); o[3] = f2bf(v[3]);
    ((u16x4*)dst)[off] = o;
}

// ---------------- fused projection GEMM ----------------
__global__ __launch_bounds__(256) void proj_gemm(
    const unsigned short* __restrict__ A,
    const unsigned short* __restrict__ Bw,
    const float* __restrict__ b0, const float* __restrict__ b1, const float* __restrict__ b2,
    unsigned short* __restrict__ Qc, unsigned short* __restrict__ Kc, unsigned short* __restrict__ VT,
    int K, int Ntot, int variant)
{
    __shared__ __align__(16) unsigned short As[4096];   // [128][32]
    __shared__ __align__(16) unsigned short Bs[4096];   // [128][32]
    const int tid = threadIdx.x, w = tid >> 6, lane = tid & 63;
    const int g = lane >> 4, c = lane & 15;
    const int m0 = blockIdx.x * 128, n0 = blockIdx.y * 128;
    const int wr = w >> 1, wc = w & 1;
    const int srow = lane >> 2, scol = (lane & 3) * 8;

    f32x4 acc[4][4];
    #pragma unroll
    for (int m = 0; m < 4; m++)
        #pragma unroll
        for (int n = 0; n < 4; n++) acc[m][n] = fzero();

    const int ch0 = w * 2, ch1 = w * 2 + 1;
    const size_t arow0 = (size_t)(m0 + ch0 * 16 + srow) * K + scol;
    const size_t arow1 = (size_t)(m0 + ch1 * 16 + srow) * K + scol;
    int bn0 = n0 + ch0 * 16 + srow; if (bn0 >= Ntot) bn0 = Ntot - 1;
    int bn1 = n0 + ch1 * 16 + srow; if (bn1 >= Ntot) bn1 = Ntot - 1;
    const size_t brow0 = (size_t)bn0 * K + scol;
    const size_t brow1 = (size_t)bn1 * K + scol;

    for (int k0 = 0; k0 < K; k0 += 32) {
        __syncthreads();
        GLDS16(A  + arow0 + k0, As + ch0 * 512);
        GLDS16(A  + arow1 + k0, As + ch1 * 512);
        GLDS16(Bw + brow0 + k0, Bs + ch0 * 512);
        GLDS16(Bw + brow1 + k0, Bs + ch1 * 512);
        __syncthreads();
        bf16x8 af[4], bfr[4];
        #pragma unroll
        for (int m = 0; m < 4; m++) af[m]  = *(const bf16x8*)&As[(wr*64 + m*16 + c)*32 + g*8];
        #pragma unroll
        for (int n = 0; n < 4; n++) bfr[n] = *(const bf16x8*)&Bs[(wc*64 + n*16 + c)*32 + g*8];
        #pragma unroll
        for (int m = 0; m < 4; m++)
            #pragma unroll
            for (int n = 0; n < 4; n++)
                acc[m][n] = __builtin_amdgcn_mfma_f32_16x16x32_bf16(af[m], bfr[n], acc[m][n], 0, 0, 0);
    }

    const int b_ = m0 >> 10;
    #pragma unroll
    for (int nf = 0; nf < 4; nf++) {
        int n = n0 + wc * 64 + nf * 16 + c;
        if (n >= Ntot) continue;
        int seg, nn;
        if (variant == 0) { seg = (n >= 1536) ? 2 : ((n >= 768) ? 1 : 0); nn = n - seg * 768; }
        else              { seg = (n >= 384)  ? 2 : ((n >= 192) ? 1 : 0); nn = n - seg * 192; }
        const float* bp = (seg == 0) ? b0 : ((seg == 1) ? b1 : b2);
        float bv = bp[nn];
        float scale = (seg == 0) ? (variant ? 0.25f : 0.125f) : 1.0f;
        int h, d;
        if (variant == 0) { h = nn >> 6; d = nn & 63; }
        else              { h = nn >> 4; d = 64 + (nn & 15); }
        #pragma unroll
        for (int m = 0; m < 4; m++) {
            int row = m0 + wr * 64 + m * 16 + 4 * g;
            int s = row & 1023;
            if (seg < 2) {
                unsigned short* dst = (seg == 0) ? Qc : Kc;
                size_t base = (size_t)(b_ * NH + h) * SEQ;
                #pragma unroll
                for (int r = 0; r < 4; r++) {
                    dst[(base + s + r) * DCAT + d] = f2bf((acc[m][nf][r] + bv) * scale);
                    if (variant == 1)
                        dst[(base + s + r) * DCAT + d + 16] = 0;   // zero pad d=80..95
                }
            } else {
                u16x4 pk;
                #pragma unroll
                for (int r = 0; r < 4; r++) pk[r] = f2bf(acc[m][nf][r] + bv);
                *(u16x4*)&VT[((size_t)(b_ * NH + h) * DV + d) * SEQ + s] = pk;
            }
        }
    }
}

// ---------------- fused attention v6: swapped ops + block-shared LDS K ----------------
// grid: 768 blocks (XCD-swizzled). 4 waves, each wave owns 32 q rows.
// K staged per-block in LDS (double-buffered, prefetch 1 tile ahead, one
// __syncthreads per 64-row tile). 3-plane layout, XOR chunk swizzle:
//   LDS slot s of row lr holds original 16B-chunk s ^ ((lr>>1)&3)  -> uniform
//   8 lanes/quad-bank on both the linear global_load_lds writes (pre-swizzled
//   per-lane global source) and the ds_read_b128 fragment reads.
__global__ __launch_bounds__(256, 3) void attn_kernel(
    const unsigned short* __restrict__ Qc,   // [BH, SEQ, 96] bf16: q/8 | lq/4 | 0
    const unsigned short* __restrict__ Kc,   // [BH, SEQ, 96] bf16: k | lk | 0
    const unsigned short* __restrict__ VT,   // [BH, 80, SEQ] bf16 (d-major)
    const float* __restrict__ mask,          // [NB, SEQ]
    float* __restrict__ ctx,                 // [NB, SEQ, 768]
    float* __restrict__ lctx,                // [NB, SEQ, 192]
    float* __restrict__ probs)               // [BH, SEQ, SEQ]
{
    __shared__ __align__(16) unsigned short Ks[2 * 6144];    // 2 x (3 planes x 64 x 32)
    __shared__ __align__(16) unsigned short pbuf[4][32][36];

    const int tid = threadIdx.x, w = tid >> 6, lane = tid & 63;
    const int g = lane >> 4, c = lane & 15;

    const int bid = blockIdx.x;
    const int xc = bid & 7, j = bid >> 3;     // j in 0..95
    const int bh = xc + 8 * (j >> 3);         // 0..95
    const int qt = j & 7;
    const int b = bh / NH, h = bh % NH;
    const int qrb = qt * 128 + w * 32;        // this wave's 32 q rows
    const float NEGF = -3.4028234663852886e38f;

    // Q fragments for both q-tiles (B-operand of swapped QK^T)
    bf16x8 qa0, qa1, qa2, qb0, qb1, qb2;
    {
        const unsigned short* qr0 = &Qc[((size_t)bh * SEQ + qrb + c) * DCAT + g * 8];
        qa0 = *(const bf16x8*)(qr0);
        qa1 = *(const bf16x8*)(qr0 + 32);
        qa2 = *(const bf16x8*)(qr0 + 64);
        const unsigned short* qr1 = qr0 + 16 * DCAT;
        qb0 = *(const bf16x8*)(qr1);
        qb1 = *(const bf16x8*)(qr1 + 32);
        qb2 = *(const bf16x8*)(qr1 + 64);
    }
    const unsigned short* Kb = Kc + (size_t)bh * SEQ * DCAT;
    const unsigned short* Vb = VT + (size_t)bh * DV * SEQ;
    const float* mk = mask + b * SEQ;

    // staging: wave w copies rows w*16..w*16+15, planes 0..2 (1 instr each)
    const int srow   = lane >> 2;                        // row within group
    const int schunk = (lane & 3) ^ ((lane >> 3) & 3);   // pre-swizzled source chunk
    const int ssrc   = (w * 16 + srow) * DCAT + schunk * 8;   // shorts, + p*32
    unsigned short* sdst = &Ks[w * 512];                      // shorts, + buf*6144 + p*2048

    // ds_read chunk slot (shorts offset within 32-short plane row)
    const int slot8 = (g ^ ((c >> 1) & 3)) * 8;

    // ---------------- pass A: row sums of exp(s) ----------------
    #pragma unroll
    for (int p = 0; p < 3; p++)
        GLDS16(Kb + ssrc + p * 32, sdst + p * 2048);
    __syncthreads();

    float sm0 = 0.f, sm1 = 0.f;
    for (int t = 0; t < 16; t++) {
        const int buf = t & 1;
        if (t < 15) {
            const unsigned short* src = Kb + (t + 1) * 6144 + ssrc;
            unsigned short* dst = sdst + (buf ^ 1) * 6144;
            #pragma unroll
            for (int p = 0; p < 3; p++)
                GLDS16(src + p * 32, dst + p * 2048);
        }
        #pragma unroll
        for (int ktl = 0; ktl < 4; ktl++) {
            const int rb = buf * 6144 + (ktl * 16 + c) * 32 + slot8;
            bf16x8 k0 = *(const bf16x8*)&Ks[rb];
            bf16x8 k1 = *(const bf16x8*)&Ks[rb + 2048];
            bf16x8 k2 = *(const bf16x8*)&Ks[rb + 4096];
            f32x4 m4 = *(const f32x4*)&mk[t * 64 + ktl * 16 + 4 * g];
            __builtin_amdgcn_s_setprio(1);
            f32x4 a0 = __builtin_amdgcn_mfma_f32_16x16x32_bf16(k0, qa0, fzero(), 0, 0, 0);
            f32x4 a1 = __builtin_amdgcn_mfma_f32_16x16x32_bf16(k1, qa1, fzero(), 0, 0, 0);
            f32x4 a2 = __builtin_amdgcn_mfma_f32_16x16x32_bf16(k2, qa2, fzero(), 0, 0, 0);
            f32x4 b0 = __builtin_amdgcn_mfma_f32_16x16x32_bf16(k0, qb0, fzero(), 0, 0, 0);
            f32x4 b1 = __builtin_amdgcn_mfma_f32_16x16x32_bf16(k1, qb1, fzero(), 0, 0, 0);
            f32x4 b2 = __builtin_amdgcn_mfma_f32_16x16x32_bf16(k2, qb2, fzero(), 0, 0, 0);
            __builtin_amdgcn_s_setprio(0);
            #pragma unroll
            for (int r = 0; r < 4; r++) {
                float bias = (1.0f - m4[r]) * NEGF;
                sm0 += __expf(a0[r] + a1[r] + a2[r] + bias);
                sm1 += __expf(b0[r] + b1[r] + b2[r] + bias);
            }
        }
        __syncthreads();
    }
    sm0 += __shfl_xor(sm0, 16); sm0 += __shfl_xor(sm0, 32);
    sm1 += __shfl_xor(sm1, 16); sm1 += __shfl_xor(sm1, 32);
    const float rinv0 = 1.0f / fmaxf(sm0, 1e-38f);
    const float rinv1 = 1.0f / fmaxf(sm1, 1e-38f);

    // ---------------- pass B: probs + PV ----------------
    f32x4 cacc0[5], cacc1[5];
    #pragma unroll
    for (int nf = 0; nf < 5; nf++) { cacc0[nf] = fzero(); cacc1[nf] = fzero(); }

    const size_t prow0 = ((size_t)bh * SEQ + qrb + c) * SEQ;
    const size_t prow1 = prow0 + 16 * SEQ;

    #pragma unroll
    for (int p = 0; p < 3; p++)
        GLDS16(Kb + ssrc + p * 32, sdst + p * 2048);
    __syncthreads();

    for (int t = 0; t < 16; t++) {
        const int buf = t & 1;
        if (t < 15) {
            const unsigned short* src = Kb + (t + 1) * 6144 + ssrc;
            unsigned short* dst = sdst + (buf ^ 1) * 6144;
            #pragma unroll
            for (int p = 0; p < 3; p++)
                GLDS16(src + p * 32, dst + p * 2048);
        }
        #pragma unroll
        for (int half = 0; half < 2; half++) {
            const int kp = t * 2 + half;
            // prefetch V fragments for this 32-k block (used after QK+softmax)
            bf16x8 vf0 = *(const bf16x8*)&Vb[(size_t)(0 * 16 + c) * SEQ + kp * 32 + g * 8];
            bf16x8 vf1 = *(const bf16x8*)&Vb[(size_t)(1 * 16 + c) * SEQ + kp * 32 + g * 8];
            bf16x8 vf2 = *(const bf16x8*)&Vb[(size_t)(2 * 16 + c) * SEQ + kp * 32 + g * 8];
            bf16x8 vf3 = *(const bf16x8*)&Vb[(size_t)(3 * 16 + c) * SEQ + kp * 32 + g * 8];
            bf16x8 vf4 = *(const bf16x8*)&Vb[(size_t)(4 * 16 + c) * SEQ + kp * 32 + g * 8];
            #pragma unroll
            for (int ph = 0; ph < 2; ph++) {
                const int ktl = half * 2 + ph;
                const int rb = buf * 6144 + (ktl * 16 + c) * 32 + slot8;
                bf16x8 k0 = *(const bf16x8*)&Ks[rb];
                bf16x8 k1 = *(const bf16x8*)&Ks[rb + 2048];
                bf16x8 k2 = *(const bf16x8*)&Ks[rb + 4096];
                f32x4 m4 = *(const f32x4*)&mk[t * 64 + ktl * 16 + 4 * g];
                __builtin_amdgcn_s_setprio(1);
                f32x4 a0 = __builtin_amdgcn_mfma_f32_16x16x32_bf16(k0, qa0, fzero(), 0, 0, 0);
                f32x4 a1 = __builtin_amdgcn_mfma_f32_16x16x32_bf16(k1, qa1, fzero(), 0, 0, 0);
                f32x4 a2 = __builtin_amdgcn_mfma_f32_16x16x32_bf16(k2, qa2, fzero(), 0, 0, 0);
                f32x4 b0 = __builtin_amdgcn_mfma_f32_16x16x32_bf16(k0, qb0, fzero(), 0, 0, 0);
                f32x4 b1 = __builtin_amdgcn_mfma_f32_16x16x32_bf16(k1, qb1, fzero(), 0, 0, 0);
                f32x4 b2 = __builtin_amdgcn_mfma_f32_16x16x32_bf16(k2, qb2, fzero(), 0, 0, 0);
                __builtin_amdgcn_s_setprio(0);
                f32x4 p0, p1;
                u16x4 h0, h1;
                #pragma unroll
                for (int r = 0; r < 4; r++) {
                    float bias = (1.0f - m4[r]) * NEGF;
                    p0[r] = __expf(a0[r] + a1[r] + a2[r] + bias) * rinv0;
                    p1[r] = __expf(b0[r] + b1[r] + b2[r] + bias) * rinv1;
                    h0[r] = f2bf(p0[r]);
                    h1[r] = f2bf(p1[r]);
                }
                *(f32x4*)&probs[prow0 + (t * 64 + ktl * 16) + 4 * g] = p0;
                *(f32x4*)&probs[prow1 + (t * 64 + ktl * 16) + 4 * g] = p1;
                *(u16x4*)&pbuf[w][c][ph * 16 + 4 * g]      = h0;
                *(u16x4*)&pbuf[w][16 + c][ph * 16 + 4 * g] = h1;
            }
            bf16x8 pa0 = *(const bf16x8*)&pbuf[w][c][g * 8];
            bf16x8 pa1 = *(const bf16x8*)&pbuf[w][16 + c][g * 8];
            __builtin_amdgcn_s_setprio(1);
            cacc0[0] = __builtin_amdgcn_mfma_f32_16x16x32_bf16(pa0, vf0, cacc0[0], 0, 0, 0);
            cacc1[0] = __builtin_amdgcn_mfma_f32_16x16x32_bf16(pa1, vf0, cacc1[0], 0, 0, 0);
            cacc0[1] = __builtin_amdgcn_mfma_f32_16x16x32_bf16(pa0, vf1, cacc0[1], 0, 0, 0);
            cacc1[1] = __builtin_amdgcn_mfma_f32_16x16x32_bf16(pa1, vf1, cacc1[1], 0, 0, 0);
            cacc0[2] = __builtin_amdgcn_mfma_f32_16x16x32_bf16(pa0, vf2, cacc0[2], 0, 0, 0);
            cacc1[2] = __builtin_amdgcn_mfma_f32_16x16x32_bf16(pa1, vf2, cacc1[2], 0, 0, 0);
            cacc0[3] = __builtin_amdgcn_mfma_f32_16x16x32_bf16(pa0, vf3, cacc0[3], 0, 0, 0);
            cacc1[3] = __builtin_amdgcn_mfma_f32_16x16x32_bf16(pa1, vf3, cacc1[3], 0, 0, 0);
            cacc0[4] = __builtin_amdgcn_mfma_f32_16x16x32_bf16(pa0, vf4, cacc0[4], 0, 0, 0);
            cacc1[4] = __builtin_amdgcn_mfma_f32_16x16x32_bf16(pa1, vf4, cacc1[4], 0, 0, 0);
            __builtin_amdgcn_s_setprio(0);
        }
        __syncthreads();
    }

    // ---- epilogue ----
    #pragma unroll
    for (int nf = 0; nf < 4; nf++)
        #pragma unroll
        for (int r = 0; r < 4; r++) {
            int q0 = qrb + 4 * g + r;
            ctx[((size_t)(b * SEQ + q0)) * 768 + h * 64 + nf * 16 + c] = cacc0[nf][r];
            ctx[((size_t)(b * SEQ + q0 + 16)) * 768 + h * 64 + nf * 16 + c] = cacc1[nf][r];
        }
    #pragma unroll
    for (int r = 0; r < 4; r++) {
        int q0 = qrb + 4 * g + r;
        lctx[((size_t)(b * SEQ + q0)) * 192 + h * 16 + c] = cacc0[4][r];
        lctx[((size_t)(b * SEQ + q0 + 16)) * 192 + h * 16 + c] = cacc1[4][r];
    }
}

// ---------------- host launch ----------------
extern "C" void kernel_launch(void* const* d_in, const int* in_sizes, int n_in,
                              void* d_out, int out_size, void* d_ws, size_t ws_size,
                              hipStream_t stream)
{
    const float* hs   = (const float*)d_in[0];
    const float* lhs  = (const float*)d_in[1];
    const float* mask = (const float*)d_in[2];
    const float* Wq   = (const float*)d_in[3];
    const float* bq   = (const float*)d_in[4];
    const float* Wk   = (const float*)d_in[5];
    const float* bk   = (const float*)d_in[6];
    const float* Wv   = (const float*)d_in[7];
    const float* bv   = (const float*)d_in[8];
    const float* Wlq  = (const float*)d_in[9];
    const float* blq  = (const float*)d_in[10];
    const float* Wlk  = (const float*)d_in[11];
    const float* blk_ = (const float*)d_in[12];
    const float* Wlv  = (const float*)d_in[13];
    const float* blv  = (const float*)d_in[14];

    float* out   = (float*)d_out;
    float* ctx   = out;
    float* lctx  = out + (size_t)NB * SEQ * 768;
    float* probs = out + (size_t)NB * SEQ * 768 + (size_t)NB * SEQ * 192;

    char* ws = (char*)d_ws;
    unsigned short* Qc     = (unsigned short*)(ws);                 // 18,874,368 B
    unsigned short* Kc     = (unsigned short*)(ws + 18874368);      // 18,874,368 B
    unsigned short* VT     = (unsigned short*)(ws + 37748736);      // 15,728,640 B
    unsigned short* hid16  = (unsigned short*)(ws + 53477376);      // 12,582,912 B
    unsigned short* lay16  = (unsigned short*)(ws + 66060288);      //  3,145,728 B
    unsigned short* wqkv16 = (unsigned short*)(ws + 69206016);      //  3,538,944 B
    unsigned short* wl16   = (unsigned short*)(ws + 72744960);      //    221,184 B

    // one fused bf16 conversion launch (8 tensors)
    cvt_all<<<dim3(9516), dim3(256), 0, stream>>>(hs, lhs, Wq, Wk, Wv, Wlq, Wlk, Wlv,
                                                  hid16, lay16, wqkv16, wl16);

    // fused projections (variant 1 writes the Qc/Kc zero pads — no memset needed)
    proj_gemm<<<dim3(64, 18), dim3(256), 0, stream>>>(hid16, wqkv16, bq, bk, bv,
                                                      Qc, Kc, VT, 768, 2304, 0);
    proj_gemm<<<dim3(64, 5),  dim3(256), 0, stream>>>(lay16, wl16, blq, blk_, blv,
                                                      Qc, Kc, VT, 192, 576, 1);

    // fused attention
    attn_kernel<<<dim3(768), dim3(256), 0, stream>>>(Qc, Kc, VT, mask, ctx, lctx, probs);
}

// Round 7
// 241.536 us; speedup vs baseline: 1.5941x; 1.0241x over previous
//
#include <hip/hip_runtime.h>

#define NH   12
#define SEQ  1024
#define NB   8
#define DCAT 96
#define DV   80

typedef __attribute__((ext_vector_type(8))) short  bf16x8;
typedef __attribute__((ext_vector_type(4))) float  f32x4;
typedef __attribute__((ext_vector_type(4))) unsigned short u16x4;

static __device__ __forceinline__ unsigned short f2bf(float x) {
    unsigned int u = __float_as_uint(x);
    u += 0x7fffu + ((u >> 16) & 1u);   // RNE
    return (unsigned short)(u >> 16);
}
static __device__ __forceinline__ f32x4 fzero() {
    f32x4 z; z[0]=0.f; z[1]=0.f; z[2]=0.f; z[3]=0.f; return z;
}
static __device__ __forceinline__ unsigned int cvtpk(float lo, float hi) {
    unsigned int r;
    asm("v_cvt_pk_bf16_f32 %0, %1, %2" : "=v"(r) : "v"(lo), "v"(hi));
    return r;
}

#define GLDS16(gp, lp) __builtin_amdgcn_global_load_lds(                      \
    (const __attribute__((address_space(1))) void*)(gp),                      \
    (__attribute__((address_space(3))) void*)(lp), 16, 0, 0)

// counted vmcnt wait (compiler memory fence so op counts stay exact)
#define WAITV(nstr) asm volatile("s_waitcnt vmcnt(" nstr ")" ::: "memory")
// raw barrier (no vmcnt drain), fenced against codegen reordering
#define SBARRIER() do {                                                       \
    __builtin_amdgcn_sched_barrier(0);                                        \
    asm volatile("" ::: "memory");                                            \
    __builtin_amdgcn_s_barrier();                                             \
    asm volatile("" ::: "memory");                                            \
    __builtin_amdgcn_sched_barrier(0);                                        \
} while (0)

// ---------------- fused f32 -> bf16 convert (all 8 tensors, 1 launch) ----------------
__global__ __launch_bounds__(256) void cvt_all(
    const float* __restrict__ hs, const float* __restrict__ lhs,
    const float* __restrict__ Wq, const float* __restrict__ Wk, const float* __restrict__ Wv,
    const float* __restrict__ Wlq, const float* __restrict__ Wlk, const float* __restrict__ Wlv,
    unsigned short* __restrict__ hid16, unsigned short* __restrict__ lay16,
    unsigned short* __restrict__ wqkv16, unsigned short* __restrict__ wl16)
{
    int i = blockIdx.x * 256 + threadIdx.x;
    const float* src; unsigned short* dst; int off;
    if      (i < 1572864) { src = hs;  dst = hid16;           off = i; }
    else if (i < 1966080) { src = lhs; dst = lay16;           off = i - 1572864; }
    else if (i < 2113536) { src = Wq;  dst = wqkv16;          off = i - 1966080; }
    else if (i < 2260992) { src = Wk;  dst = wqkv16 + 589824; off = i - 2113536; }
    else if (i < 2408448) { src = Wv;  dst = wqkv16 + 1179648;off = i - 2260992; }
    else if (i < 2417664) { src = Wlq; dst = wl16;            off = i - 2408448; }
    else if (i < 2426880) { src = Wlk; dst = wl16 + 36864;    off = i - 2417664; }
    else if (i < 2436096) { src = Wlv; dst = wl16 + 73728;    off = i - 2426880; }
    else return;
    f32x4 v = ((const f32x4*)src)[off];
    u16x4 o;
    o[0] = f2bf(v[0]); o[1] = f2bf(v[1]); o[2] = f2bf(v[2]); o[3] = f2bf(v[3]);
    ((u16x4*)dst)[off] = o;
}

// ---------------- fused projection GEMM ----------------
__global__ __launch_bounds__(256) void proj_gemm(
    const unsigned short* __restrict__ A,
    const unsigned short* __restrict__ Bw,
    const float* __restrict__ b0, const float* __restrict__ b1, const float* __restrict__ b2,
    unsigned short* __restrict__ Qc, unsigned short* __restrict__ Kc, unsigned short* __restrict__ VT,
    int K, int Ntot, int variant)
{
    __shared__ __align__(16) unsigned short As[4096];   // [128][32]
    __shared__ __align__(16) unsigned short Bs[4096];   // [128][32]
    const int tid = threadIdx.x, w = tid >> 6, lane = tid & 63;
    const int g = lane >> 4, c = lane & 15;
    const int m0 = blockIdx.x * 128, n0 = blockIdx.y * 128;
    const int wr = w >> 1, wc = w & 1;
    const int srow = lane >> 2, scol = (lane & 3) * 8;

    f32x4 acc[4][4];
    #pragma unroll
    for (int m = 0; m < 4; m++)
        #pragma unroll
        for (int n = 0; n < 4; n++) acc[m][n] = fzero();

    const int ch0 = w * 2, ch1 = w * 2 + 1;
    const size_t arow0 = (size_t)(m0 + ch0 * 16 + srow) * K + scol;
    const size_t arow1 = (size_t)(m0 + ch1 * 16 + srow) * K + scol;
    int bn0 = n0 + ch0 * 16 + srow; if (bn0 >= Ntot) bn0 = Ntot - 1;
    int bn1 = n0 + ch1 * 16 + srow; if (bn1 >= Ntot) bn1 = Ntot - 1;
    const size_t brow0 = (size_t)bn0 * K + scol;
    const size_t brow1 = (size_t)bn1 * K + scol;

    for (int k0 = 0; k0 < K; k0 += 32) {
        __syncthreads();
        GLDS16(A  + arow0 + k0, As + ch0 * 512);
        GLDS16(A  + arow1 + k0, As + ch1 * 512);
        GLDS16(Bw + brow0 + k0, Bs + ch0 * 512);
        GLDS16(Bw + brow1 + k0, Bs + ch1 * 512);
        __syncthreads();
        bf16x8 af[4], bfr[4];
        #pragma unroll
        for (int m = 0; m < 4; m++) af[m]  = *(const bf16x8*)&As[(wr*64 + m*16 + c)*32 + g*8];
        #pragma unroll
        for (int n = 0; n < 4; n++) bfr[n] = *(const bf16x8*)&Bs[(wc*64 + n*16 + c)*32 + g*8];
        #pragma unroll
        for (int m = 0; m < 4; m++)
            #pragma unroll
            for (int n = 0; n < 4; n++)
                acc[m][n] = __builtin_amdgcn_mfma_f32_16x16x32_bf16(af[m], bfr[n], acc[m][n], 0, 0, 0);
    }

    const int b_ = m0 >> 10;
    #pragma unroll
    for (int nf = 0; nf < 4; nf++) {
        int n = n0 + wc * 64 + nf * 16 + c;
        if (n >= Ntot) continue;
        int seg, nn;
        if (variant == 0) { seg = (n >= 1536) ? 2 : ((n >= 768) ? 1 : 0); nn = n - seg * 768; }
        else              { seg = (n >= 384)  ? 2 : ((n >= 192) ? 1 : 0); nn = n - seg * 192; }
        const float* bp = (seg == 0) ? b0 : ((seg == 1) ? b1 : b2);
        float bv = bp[nn];
        float scale = (seg == 0) ? (variant ? 0.25f : 0.125f) : 1.0f;
        int h, d;
        if (variant == 0) { h = nn >> 6; d = nn & 63; }
        else              { h = nn >> 4; d = 64 + (nn & 15); }
        #pragma unroll
        for (int m = 0; m < 4; m++) {
            int row = m0 + wr * 64 + m * 16 + 4 * g;
            int s = row & 1023;
            if (seg < 2) {
                unsigned short* dst = (seg == 0) ? Qc : Kc;
                size_t base = (size_t)(b_ * NH + h) * SEQ;
                #pragma unroll
                for (int r = 0; r < 4; r++) {
                    dst[(base + s + r) * DCAT + d] = f2bf((acc[m][nf][r] + bv) * scale);
                    if (variant == 1)
                        dst[(base + s + r) * DCAT + d + 16] = 0;   // zero pad d=80..95
                }
            } else {
                u16x4 pk;
                #pragma unroll
                for (int r = 0; r < 4; r++) pk[r] = f2bf(acc[m][nf][r] + bv);
                *(u16x4*)&VT[((size_t)(b_ * NH + h) * DV + d) * SEQ + s] = pk;
            }
        }
    }
}

// ---------------- fused attention v7: counted-vmcnt barriers ----------------
// Same data layout as v6 (swapped MFMA ops, 32 q-rows/wave, LDS K dbuf with
// XOR chunk swizzle). Barriers are raw s_barrier + literal s_waitcnt vmcnt(N)
// counting exactly the vmem ops issued after the global_load_lds batch that
// must retire — probs stores / V loads never get drained (T3/T4).
// Per-tile vmem op counts (order pinned by sched_barrier + memory-clobber asm):
//   pass A: GLDS[3] | 4 mask loads            -> WAITV 7 (last tile: 4)
//   pass B: GLDS[3] | 10 V + 4 mask + 8 store -> WAITV 25 (last tile: 22)
__global__ __launch_bounds__(256, 3) void attn_kernel(
    const unsigned short* __restrict__ Qc,   // [BH, SEQ, 96] bf16: q/8 | lq/4 | 0
    const unsigned short* __restrict__ Kc,   // [BH, SEQ, 96] bf16: k | lk | 0
    const unsigned short* __restrict__ VT,   // [BH, 80, SEQ] bf16 (d-major)
    const float* __restrict__ mask,          // [NB, SEQ]
    float* __restrict__ ctx,                 // [NB, SEQ, 768]
    float* __restrict__ lctx,                // [NB, SEQ, 192]
    float* __restrict__ probs)               // [BH, SEQ, SEQ]
{
    __shared__ __align__(16) unsigned short Ks[2 * 6144];    // 2 x (3 planes x 64 x 32)
    __shared__ __align__(16) unsigned short pbuf[4][32][36];

    const int tid = threadIdx.x, w = tid >> 6, lane = tid & 63;
    const int g = lane >> 4, c = lane & 15;

    const int bid = blockIdx.x;
    const int xc = bid & 7, j = bid >> 3;     // j in 0..95
    const int bh = xc + 8 * (j >> 3);         // 0..95
    const int qt = j & 7;
    const int b = bh / NH, h = bh % NH;
    const int qrb = qt * 128 + w * 32;        // this wave's 32 q rows
    const float NEGF = -3.4028234663852886e38f;

    // Q fragments for both q-tiles (B-operand of swapped QK^T)
    bf16x8 qa0, qa1, qa2, qb0, qb1, qb2;
    {
        const unsigned short* qr0 = &Qc[((size_t)bh * SEQ + qrb + c) * DCAT + g * 8];
        qa0 = *(const bf16x8*)(qr0);
        qa1 = *(const bf16x8*)(qr0 + 32);
        qa2 = *(const bf16x8*)(qr0 + 64);
        const unsigned short* qr1 = qr0 + 16 * DCAT;
        qb0 = *(const bf16x8*)(qr1);
        qb1 = *(const bf16x8*)(qr1 + 32);
        qb2 = *(const bf16x8*)(qr1 + 64);
    }
    const unsigned short* Kb = Kc + (size_t)bh * SEQ * DCAT;
    const unsigned short* Vb = VT + (size_t)bh * DV * SEQ;
    const float* mk = mask + b * SEQ;

    // staging: wave w copies rows w*16..w*16+15, planes 0..2 (1 instr each)
    const int srow   = lane >> 2;                        // row within group
    const int schunk = (lane & 3) ^ ((lane >> 3) & 3);   // pre-swizzled source chunk
    const int ssrc   = (w * 16 + srow) * DCAT + schunk * 8;   // shorts, + p*32
    unsigned short* sdst = &Ks[w * 512];                      // shorts, + buf*6144 + p*2048

    // ds_read chunk slot (shorts offset within 32-short plane row)
    const int slot8 = (g ^ ((c >> 1) & 3)) * 8;

    // ---------------- pass A: row sums of exp(s) ----------------
    #pragma unroll
    for (int p = 0; p < 3; p++)
        GLDS16(Kb + ssrc + p * 32, sdst + p * 2048);
    __builtin_amdgcn_sched_barrier(0);
    WAITV("0");

    float sm0 = 0.f, sm1 = 0.f;
    for (int t = 0; t < 16; t++) {
        const int buf = t & 1;
        SBARRIER();
        if (t < 15) {
            const unsigned short* src = Kb + (t + 1) * 6144 + ssrc;
            unsigned short* dst = sdst + (buf ^ 1) * 6144;
            #pragma unroll
            for (int p = 0; p < 3; p++)
                GLDS16(src + p * 32, dst + p * 2048);
            __builtin_amdgcn_sched_barrier(0);
            WAITV("7");
        } else {
            WAITV("4");
        }
        #pragma unroll
        for (int ktl = 0; ktl < 4; ktl++) {
            const int rb = buf * 6144 + (ktl * 16 + c) * 32 + slot8;
            bf16x8 k0 = *(const bf16x8*)&Ks[rb];
            bf16x8 k1 = *(const bf16x8*)&Ks[rb + 2048];
            bf16x8 k2 = *(const bf16x8*)&Ks[rb + 4096];
            f32x4 m4 = *(const f32x4*)&mk[t * 64 + ktl * 16 + 4 * g];
            __builtin_amdgcn_s_setprio(1);
            f32x4 a0 = __builtin_amdgcn_mfma_f32_16x16x32_bf16(k0, qa0, fzero(), 0, 0, 0);
            f32x4 a1 = __builtin_amdgcn_mfma_f32_16x16x32_bf16(k1, qa1, fzero(), 0, 0, 0);
            f32x4 a2 = __builtin_amdgcn_mfma_f32_16x16x32_bf16(k2, qa2, fzero(), 0, 0, 0);
            f32x4 b0 = __builtin_amdgcn_mfma_f32_16x16x32_bf16(k0, qb0, fzero(), 0, 0, 0);
            f32x4 b1 = __builtin_amdgcn_mfma_f32_16x16x32_bf16(k1, qb1, fzero(), 0, 0, 0);
            f32x4 b2 = __builtin_amdgcn_mfma_f32_16x16x32_bf16(k2, qb2, fzero(), 0, 0, 0);
            __builtin_amdgcn_s_setprio(0);
            #pragma unroll
            for (int r = 0; r < 4; r++) {
                float bias = (1.0f - m4[r]) * NEGF;
                sm0 += __expf(a0[r] + a1[r] + a2[r] + bias);
                sm1 += __expf(b0[r] + b1[r] + b2[r] + bias);
            }
        }
    }
    sm0 += __shfl_xor(sm0, 16); sm0 += __shfl_xor(sm0, 32);
    sm1 += __shfl_xor(sm1, 16); sm1 += __shfl_xor(sm1, 32);
    const float rinv0 = 1.0f / fmaxf(sm0, 1e-38f);
    const float rinv1 = 1.0f / fmaxf(sm1, 1e-38f);

    // ---------------- pass B: probs + PV ----------------
    f32x4 cacc0[5], cacc1[5];
    #pragma unroll
    for (int nf = 0; nf < 5; nf++) { cacc0[nf] = fzero(); cacc1[nf] = fzero(); }

    const size_t prow0 = ((size_t)bh * SEQ + qrb + c) * SEQ;
    const size_t prow1 = prow0 + 16 * SEQ;

    #pragma unroll
    for (int p = 0; p < 3; p++)
        GLDS16(Kb + ssrc + p * 32, sdst + p * 2048);
    __builtin_amdgcn_sched_barrier(0);
    WAITV("0");

    for (int t = 0; t < 16; t++) {
        const int buf = t & 1;
        SBARRIER();
        if (t < 15) {
            const unsigned short* src = Kb + (t + 1) * 6144 + ssrc;
            unsigned short* dst = sdst + (buf ^ 1) * 6144;
            #pragma unroll
            for (int p = 0; p < 3; p++)
                GLDS16(src + p * 32, dst + p * 2048);
            __builtin_amdgcn_sched_barrier(0);
            WAITV("25");
        } else {
            WAITV("22");
        }
        #pragma unroll
        for (int half = 0; half < 2; half++) {
            const int kp = t * 2 + half;
            // prefetch V fragments for this 32-k block (used after QK+softmax)
            bf16x8 vf0 = *(const bf16x8*)&Vb[(size_t)(0 * 16 + c) * SEQ + kp * 32 + g * 8];
            bf16x8 vf1 = *(const bf16x8*)&Vb[(size_t)(1 * 16 + c) * SEQ + kp * 32 + g * 8];
            bf16x8 vf2 = *(const bf16x8*)&Vb[(size_t)(2 * 16 + c) * SEQ + kp * 32 + g * 8];
            bf16x8 vf3 = *(const bf16x8*)&Vb[(size_t)(3 * 16 + c) * SEQ + kp * 32 + g * 8];
            bf16x8 vf4 = *(const bf16x8*)&Vb[(size_t)(4 * 16 + c) * SEQ + kp * 32 + g * 8];
            #pragma unroll
            for (int ph = 0; ph < 2; ph++) {
                const int ktl = half * 2 + ph;
                const int rb = buf * 6144 + (ktl * 16 + c) * 32 + slot8;
                bf16x8 k0 = *(const bf16x8*)&Ks[rb];
                bf16x8 k1 = *(const bf16x8*)&Ks[rb + 2048];
                bf16x8 k2 = *(const bf16x8*)&Ks[rb + 4096];
                f32x4 m4 = *(const f32x4*)&mk[t * 64 + ktl * 16 + 4 * g];
                __builtin_amdgcn_s_setprio(1);
                f32x4 a0 = __builtin_amdgcn_mfma_f32_16x16x32_bf16(k0, qa0, fzero(), 0, 0, 0);
                f32x4 a1 = __builtin_amdgcn_mfma_f32_16x16x32_bf16(k1, qa1, fzero(), 0, 0, 0);
                f32x4 a2 = __builtin_amdgcn_mfma_f32_16x16x32_bf16(k2, qa2, fzero(), 0, 0, 0);
                f32x4 b0 = __builtin_amdgcn_mfma_f32_16x16x32_bf16(k0, qb0, fzero(), 0, 0, 0);
                f32x4 b1 = __builtin_amdgcn_mfma_f32_16x16x32_bf16(k1, qb1, fzero(), 0, 0, 0);
                f32x4 b2 = __builtin_amdgcn_mfma_f32_16x16x32_bf16(k2, qb2, fzero(), 0, 0, 0);
                __builtin_amdgcn_s_setprio(0);
                f32x4 p0, p1;
                #pragma unroll
                for (int r = 0; r < 4; r++) {
                    float bias = (1.0f - m4[r]) * NEGF;
                    p0[r] = __expf(a0[r] + a1[r] + a2[r] + bias) * rinv0;
                    p1[r] = __expf(b0[r] + b1[r] + b2[r] + bias) * rinv1;
                }
                *(f32x4*)&probs[prow0 + (t * 64 + ktl * 16) + 4 * g] = p0;
                *(f32x4*)&probs[prow1 + (t * 64 + ktl * 16) + 4 * g] = p1;
                uint2 hh0, hh1;
                hh0.x = cvtpk(p0[0], p0[1]); hh0.y = cvtpk(p0[2], p0[3]);
                hh1.x = cvtpk(p1[0], p1[1]); hh1.y = cvtpk(p1[2], p1[3]);
                *(uint2*)&pbuf[w][c][ph * 16 + 4 * g]      = hh0;
                *(uint2*)&pbuf[w][16 + c][ph * 16 + 4 * g] = hh1;
            }
            bf16x8 pa0 = *(const bf16x8*)&pbuf[w][c][g * 8];
            bf16x8 pa1 = *(const bf16x8*)&pbuf[w][16 + c][g * 8];
            __builtin_amdgcn_s_setprio(1);
            cacc0[0] = __builtin_amdgcn_mfma_f32_16x16x32_bf16(pa0, vf0, cacc0[0], 0, 0, 0);
            cacc1[0] = __builtin_amdgcn_mfma_f32_16x16x32_bf16(pa1, vf0, cacc1[0], 0, 0, 0);
            cacc0[1] = __builtin_amdgcn_mfma_f32_16x16x32_bf16(pa0, vf1, cacc0[1], 0, 0, 0);
            cacc1[1] = __builtin_amdgcn_mfma_f32_16x16x32_bf16(pa1, vf1, cacc1[1], 0, 0, 0);
            cacc0[2] = __builtin_amdgcn_mfma_f32_16x16x32_bf16(pa0, vf2, cacc0[2], 0, 0, 0);
            cacc1[2] = __builtin_amdgcn_mfma_f32_16x16x32_bf16(pa1, vf2, cacc1[2], 0, 0, 0);
            cacc0[3] = __builtin_amdgcn_mfma_f32_16x16x32_bf16(pa0, vf3, cacc0[3], 0, 0, 0);
            cacc1[3] = __builtin_amdgcn_mfma_f32_16x16x32_bf16(pa1, vf3, cacc1[3], 0, 0, 0);
            cacc0[4] = __builtin_amdgcn_mfma_f32_16x16x32_bf16(pa0, vf4, cacc0[4], 0, 0, 0);
            cacc1[4] = __builtin_amdgcn_mfma_f32_16x16x32_bf16(pa1, vf4, cacc1[4], 0, 0, 0);
            __builtin_amdgcn_s_setprio(0);
        }
    }

    // ---- epilogue ----
    #pragma unroll
    for (int nf = 0; nf < 4; nf++)
        #pragma unroll
        for (int r = 0; r < 4; r++) {
            int q0 = qrb + 4 * g + r;
            ctx[((size_t)(b * SEQ + q0)) * 768 + h * 64 + nf * 16 + c] = cacc0[nf][r];
            ctx[((size_t)(b * SEQ + q0 + 16)) * 768 + h * 64 + nf * 16 + c] = cacc1[nf][r];
        }
    #pragma unroll
    for (int r = 0; r < 4; r++) {
        int q0 = qrb + 4 * g + r;
        lctx[((size_t)(b * SEQ + q0)) * 192 + h * 16 + c] = cacc0[4][r];
        lctx[((size_t)(b * SEQ + q0 + 16)) * 192 + h * 16 + c] = cacc1[4][r];
    }
}

// ---------------- host launch ----------------
extern "C" void kernel_launch(void* const* d_in, const int* in_sizes, int n_in,
                              void* d_out, int out_size, void* d_ws, size_t ws_size,
                              hipStream_t stream)
{
    const float* hs   = (const float*)d_in[0];
    const float* lhs  = (const float*)d_in[1];
    const float* mask = (const float*)d_in[2];
    const float* Wq   = (const float*)d_in[3];
    const float* bq   = (const float*)d_in[4];
    const float* Wk   = (const float*)d_in[5];
    const float* bk   = (const float*)d_in[6];
    const float* Wv   = (const float*)d_in[7];
    const float* bv   = (const float*)d_in[8];
    const float* Wlq  = (const float*)d_in[9];
    const float* blq  = (const float*)d_in[10];
    const float* Wlk  = (const float*)d_in[11];
    const float* blk_ = (const float*)d_in[12];
    const float* Wlv  = (const float*)d_in[13];
    const float* blv  = (const float*)d_in[14];

    float* out   = (float*)d_out;
    float* ctx   = out;
    float* lctx  = out + (size_t)NB * SEQ * 768;
    float* probs = out + (size_t)NB * SEQ * 768 + (size_t)NB * SEQ * 192;

    char* ws = (char*)d_ws;
    unsigned short* Qc     = (unsigned short*)(ws);                 // 18,874,368 B
    unsigned short* Kc     = (unsigned short*)(ws + 18874368);      // 18,874,368 B
    unsigned short* VT     = (unsigned short*)(ws + 37748736);      // 15,728,640 B
    unsigned short* hid16  = (unsigned short*)(ws + 53477376);      // 12,582,912 B
    unsigned short* lay16  = (unsigned short*)(ws + 66060288);      //  3,145,728 B
    unsigned short* wqkv16 = (unsigned short*)(ws + 69206016);      //  3,538,944 B
    unsigned short* wl16   = (unsigned short*)(ws + 72744960);      //    221,184 B

    // one fused bf16 conversion launch (8 tensors)
    cvt_all<<<dim3(9516), dim3(256), 0, stream>>>(hs, lhs, Wq, Wk, Wv, Wlq, Wlk, Wlv,
                                                  hid16, lay16, wqkv16, wl16);

    // fused projections (variant 1 writes the Qc/Kc zero pads — no memset needed)
    proj_gemm<<<dim3(64, 18), dim3(256), 0, stream>>>(hid16, wqkv16, bq, bk, bv,
                                                      Qc, Kc, VT, 768, 2304, 0);
    proj_gemm<<<dim3(64, 5),  dim3(256), 0, stream>>>(lay16, wl16, blq, blk_, blv,
                                                      Qc, Kc, VT, 192, 576, 1);

    // fused attention
    attn_kernel<<<dim3(768), dim3(256), 0, stream>>>(Qc, Kc, VT, mask, ctx, lctx, probs);
}